// Round 6
// baseline (18566.139 us; speedup 1.0000x reference)
//
#include <hip/hip_runtime.h>
#include <math.h>

// KNRM-style ranker, fp32 end-to-end (kernel-0 sigma=1e-4 makes sim
// precision-critical: bf16/MFMA would flip exp-window hits).
// R6 vs R5 (9.68ms): GEMM staging rebuilt on the m97 recipe --
// global_load_lds(16B) direct-to-LDS, BK=32 row-major [rows][32] tiles,
// XOR bank-swizzle (slot ^= (row>>2)&7) applied to BOTH the per-lane
// global source and the LDS reads (linear LDS dest, rule #21).
// Single-buffered, 2 barriers/K-tile. Applied to k_gemm (QKV/W1) and
// k_gemm_ln (Wo/W2). Attention/score/embed unchanged from R5.

#define DMODEL 256
typedef float f32x4 __attribute__((ext_vector_type(4)));

__device__ __forceinline__ void gload16(const float* g, float* l) {
  __builtin_amdgcn_global_load_lds(
      (const __attribute__((address_space(1))) void*)g,
      (__attribute__((address_space(3))) void*)l, 16, 0, 0);
}

// ---------------- embed + positional encoding (4 tokens / block) ------------
__global__ __launch_bounds__(256) void k_embed(const int* __restrict__ ids,
    const float* __restrict__ emb, float* __restrict__ out_x, int S) {
  int tid = threadIdx.x;
  int tok = blockIdx.x * 4 + (tid >> 6);
  int lane = tid & 63;
  int d0 = lane * 4;
  int id = ids[tok];
  float m = id > 0 ? 1.f : 0.f;
  const float* ep = emb + (size_t)id * DMODEL + d0;
  float4 e = *(const float4*)ep;
  int s = tok % S;
  float o[4];
  float ev[4] = {e.x, e.y, e.z, e.w};
#pragma unroll
  for (int j = 0; j < 4; ++j) {
    int d = d0 + j;
    int i2 = d & ~1;
    float freq = expf((float)i2 * (-9.210340371976184f / 256.f));
    float ang = (float)s * freq;
    float pe = (d & 1) ? cosf(ang) : sinf(ang);
    o[j] = 2.f * ev[j] * m + pe;
  }
  *(float4*)(out_x + (size_t)tok * DMODEL + d0) = *(float4*)o;
}

// ---------------- fp32 GEMM: out[M,N] = X[M,K] @ W[N,K]^T + bias ------------
// 128x128xBK32 tile, 256 threads, 8x8 micro (4+4 split).
// LDS layout: row-major [128 rows][32 floats]; row = 8 slots of 16B that map
// 1:1 onto the 32 banks. Slot holding global k-slice s sits at position
// s ^ ((row>>2)&7)  (involution; applied on the global SOURCE address for
// the linear global_load_lds dest, and again on the LDS READ address).
// Read conflicts: A reads 16-lane broadcast + 2-way; B reads 2-way (free).
// Requires M%128==0, N%128==0, K%32==0.
template<bool RELU>
__global__ __launch_bounds__(256) void k_gemm(const float* __restrict__ X,
    const float* __restrict__ W, const float* __restrict__ bias,
    float* __restrict__ out, int M, int N, int K) {
  __shared__ float As[128 * 32];
  __shared__ float Bs[128 * 32];
  const int tid = threadIdx.x;
  const int n0 = blockIdx.x * 128;
  const int m0 = blockIdx.y * 128;
  const int tx = tid & 15, ty = tid >> 4;
  const int wid = tid >> 6;

  // staging: call c covers rows c*32+(tid>>3); lane slot tid&7 fetches
  // global slice (tid&7) ^ ((row>>2)&7) = (tid&7) ^ ((tid>>5)&7)
  const int srow = tid >> 3;
  const int sslc = (tid & 7) ^ ((tid >> 5) & 7);
  const float* Xp = X + (size_t)(m0 + srow) * K + sslc * 4;
  const float* Wp = W + (size_t)(n0 + srow) * K + sslc * 4;
  float* aDst = As + wid * 256;   // + c*1024 per call (floats)
  float* bDst = Bs + wid * 256;

  float acc[8][8];
#pragma unroll
  for (int i = 0; i < 8; ++i)
#pragma unroll
    for (int j = 0; j < 8; ++j) acc[i][j] = 0.f;

  const int sa = (ty & 7) << 2;   // read-side swizzle, rows ty*4+i / +64
  const int sb = (tx & 7) << 2;   // rows tx*4+j / +64

  for (int kt = 0; kt < K; kt += 32) {
    if (kt) __syncthreads();      // LDS reuse: prior compute must be done
#pragma unroll
    for (int c = 0; c < 4; ++c) {
      gload16(Xp + kt + (size_t)c * 32 * K, aDst + c * 1024);
      gload16(Wp + kt + (size_t)c * 32 * K, bDst + c * 1024);
    }
    __syncthreads();              // drains vmcnt -> tile visible
#pragma unroll
    for (int g = 0; g < 8; ++g) {
      const int ga = (g << 2) ^ sa;
      const int gb = (g << 2) ^ sb;
      f32x4 a0[4], a1[4], b0[4], b1[4];
#pragma unroll
      for (int i = 0; i < 4; ++i) {
        a0[i] = *(const f32x4*)&As[(ty * 4 + i) * 32 + ga];
        a1[i] = *(const f32x4*)&As[(64 + ty * 4 + i) * 32 + ga];
        b0[i] = *(const f32x4*)&Bs[(tx * 4 + i) * 32 + gb];
        b1[i] = *(const f32x4*)&Bs[(64 + tx * 4 + i) * 32 + gb];
      }
#pragma unroll
      for (int kk = 0; kk < 4; ++kk)
#pragma unroll
        for (int i = 0; i < 4; ++i)
#pragma unroll
          for (int j = 0; j < 4; ++j) {
            acc[i][j]         += a0[i][kk] * b0[j][kk];
            acc[i][j + 4]     += a0[i][kk] * b1[j][kk];
            acc[i + 4][j]     += a1[i][kk] * b0[j][kk];
            acc[i + 4][j + 4] += a1[i][kk] * b1[j][kk];
          }
    }
  }

#pragma unroll
  for (int i = 0; i < 8; ++i) {
    int mr = m0 + ((i < 4) ? (ty * 4 + i) : (64 + ty * 4 + i - 4));
#pragma unroll
    for (int jb = 0; jb < 2; ++jb) {
      int nc = n0 + jb * 64 + tx * 4;
      float4 bz = *(const float4*)(bias + nc);
      float4 o4;
      o4.x = acc[i][jb * 4 + 0] + bz.x;
      o4.y = acc[i][jb * 4 + 1] + bz.y;
      o4.z = acc[i][jb * 4 + 2] + bz.z;
      o4.w = acc[i][jb * 4 + 3] + bz.w;
      if (RELU) {
        o4.x = fmaxf(o4.x, 0.f); o4.y = fmaxf(o4.y, 0.f);
        o4.z = fmaxf(o4.z, 0.f); o4.w = fmaxf(o4.w, 0.f);
      }
      *(float4*)(out + (size_t)mr * N + nc) = o4;
    }
  }
}

// ---------------- GEMM (N=256) fused bias + residual + LayerNorm ------------
// Same staging/swizzle recipe; 64(M) x 256(N) tile, A=64x32 (2 calls),
// B=256x32 (8 calls), 40KB LDS. Epilogue: in-wave 16-lane LN (R5-proven).
__global__ __launch_bounds__(256) void k_gemm_ln(const float* __restrict__ X,
    const float* __restrict__ W, const float* __restrict__ bias,
    float* __restrict__ xres, const float* __restrict__ lns,
    const float* __restrict__ lnb, int M, int K) {
  __shared__ float As[64 * 32];
  __shared__ float Bs[256 * 32];
  const int tid = threadIdx.x;
  const int m0 = blockIdx.x * 64;
  const int tx = tid & 15, ty = tid >> 4;
  const int wid = tid >> 6;
  const int srow = tid >> 3;
  const int sslc = (tid & 7) ^ ((tid >> 5) & 7);
  const float* Xp = X + (size_t)(m0 + srow) * K + sslc * 4;
  const float* Wp = W + (size_t)srow * K + sslc * 4;   // all 256 N-rows
  float* aDst = As + wid * 256;
  float* bDst = Bs + wid * 256;

  f32x4 acc[4][4];
#pragma unroll
  for (int r = 0; r < 4; ++r)
#pragma unroll
    for (int q = 0; q < 4; ++q) acc[r][q] = 0.f;

  const int sa = (ty & 7) << 2;
  const int sb = (tx & 7) << 2;

  for (int kt = 0; kt < K; kt += 32) {
    if (kt) __syncthreads();
#pragma unroll
    for (int c = 0; c < 2; ++c)
      gload16(Xp + kt + (size_t)c * 32 * K, aDst + c * 1024);
#pragma unroll
    for (int c = 0; c < 8; ++c)
      gload16(Wp + kt + (size_t)c * 32 * K, bDst + c * 1024);
    __syncthreads();
#pragma unroll
    for (int g = 0; g < 8; ++g) {
      const int ga = (g << 2) ^ sa;
      const int gb = (g << 2) ^ sb;
      f32x4 av[4];
#pragma unroll
      for (int r = 0; r < 4; ++r)
        av[r] = *(const f32x4*)&As[(ty * 4 + r) * 32 + ga];
#pragma unroll
      for (int q = 0; q < 4; ++q) {
        f32x4 bq[4];
#pragma unroll
        for (int j = 0; j < 4; ++j)
          bq[j] = *(const f32x4*)&Bs[(q * 64 + tx * 4 + j) * 32 + gb];
#pragma unroll
        for (int kk = 0; kk < 4; ++kk)
#pragma unroll
          for (int r = 0; r < 4; ++r) {
            acc[r][q][0] += av[r][kk] * bq[0][kk];
            acc[r][q][1] += av[r][kk] * bq[1][kk];
            acc[r][q][2] += av[r][kk] * bq[2][kk];
            acc[r][q][3] += av[r][kk] * bq[3][kk];
          }
      }
    }
  }

  // epilogue: v = acc + bias + xres; LN per row, 16-lane shfl reduce
  f32x4 bza[4], sca[4], lba[4];
#pragma unroll
  for (int q = 0; q < 4; ++q) {
    int c = q * 64 + tx * 4;
    bza[q] = *(const f32x4*)(bias + c);
    sca[q] = *(const f32x4*)(lns + c);
    lba[q] = *(const f32x4*)(lnb + c);
  }
#pragma unroll
  for (int r = 0; r < 4; ++r) {
    size_t row = (size_t)m0 + ty * 4 + r;
    f32x4 v[4];
    float ps = 0.f;
#pragma unroll
    for (int q = 0; q < 4; ++q) {
      f32x4 xr = *(const f32x4*)(xres + row * 256 + q * 64 + tx * 4);
      v[q] = acc[r][q] + bza[q] + xr;
      ps += v[q][0] + v[q][1] + v[q][2] + v[q][3];
    }
    ps += __shfl_xor(ps, 1); ps += __shfl_xor(ps, 2);
    ps += __shfl_xor(ps, 4); ps += __shfl_xor(ps, 8);
    float mean = ps * (1.f / 256.f);
    float ss = 0.f;
#pragma unroll
    for (int q = 0; q < 4; ++q) {
      v[q] -= mean;
      ss += v[q][0] * v[q][0] + v[q][1] * v[q][1]
          + v[q][2] * v[q][2] + v[q][3] * v[q][3];
    }
    ss += __shfl_xor(ss, 1); ss += __shfl_xor(ss, 2);
    ss += __shfl_xor(ss, 4); ss += __shfl_xor(ss, 8);
    float rs = rsqrtf(ss * (1.f / 256.f) + 1e-5f);
#pragma unroll
    for (int q = 0; q < 4; ++q) {
      f32x4 y = v[q] * rs * sca[q] + lba[q];
      *(f32x4*)(xres + row * 256 + q * 64 + tx * 4) = y;
    }
  }
}

// ---------------- fused attention (R1/R3-proven) ----------------
template<int NR>
__global__ __launch_bounds__(128) void k_attn(const float* __restrict__ qkv,
    float* __restrict__ o, int S, int b0) {
  __shared__ float Ks[256 * 32];
  __shared__ float Vs[256 * 32];
  int bl = blockIdx.x >> 3;
  int h = blockIdx.x & 7;
  int tid = threadIdx.x;
  const float* base = qkv + (size_t)bl * S * 768;
  int hc = h * 32;
  for (int f = tid; f < S * 32; f += 128) {
    int s = f >> 5, e = f & 31;
    Ks[f] = base[(size_t)s * 768 + 256 + hc + e];
    Vs[f] = base[(size_t)s * 768 + 512 + hc + e];
  }
  __syncthreads();
  if (tid >= S) return;
  const float scale = 0.17677669529663687f;
  float q[NR][32], acc[NR][32], m[NR], l[NR];
#pragma unroll
  for (int r = 0; r < NR; ++r) {
    int row = tid + 128 * r;
    const float4* qp = (const float4*)(base + (size_t)row * 768 + hc);
#pragma unroll
    for (int w = 0; w < 8; ++w) {
      float4 t = qp[w];
      q[r][4 * w] = t.x; q[r][4 * w + 1] = t.y; q[r][4 * w + 2] = t.z; q[r][4 * w + 3] = t.w;
    }
    m[r] = -1e30f; l[r] = 0.f;
#pragma unroll
    for (int e = 0; e < 32; ++e) acc[r][e] = 0.f;
  }
  for (int j = 0; j < S; ++j) {
    float kv[32];
    const float4* kp = (const float4*)&Ks[j * 32];
#pragma unroll
    for (int w = 0; w < 8; ++w) {
      float4 t = kp[w];
      kv[4 * w] = t.x; kv[4 * w + 1] = t.y; kv[4 * w + 2] = t.z; kv[4 * w + 3] = t.w;
    }
    float p[NR];
#pragma unroll
    for (int r = 0; r < NR; ++r) {
      float dot = 0.f;
#pragma unroll
      for (int e = 0; e < 32; ++e) dot += q[r][e] * kv[e];
      float s_ = dot * scale;
      float mn = fmaxf(m[r], s_);
      p[r] = __expf(s_ - mn);
      if (mn > m[r]) {
        float al = __expf(m[r] - mn);
        l[r] *= al;
#pragma unroll
        for (int e = 0; e < 32; ++e) acc[r][e] *= al;
        m[r] = mn;
      }
      l[r] += p[r];
    }
    const float4* vp = (const float4*)&Vs[j * 32];
#pragma unroll
    for (int w = 0; w < 8; ++w) {
      float4 t = vp[w];
#pragma unroll
      for (int r = 0; r < NR; ++r) {
        acc[r][4 * w]     += p[r] * t.x;
        acc[r][4 * w + 1] += p[r] * t.y;
        acc[r][4 * w + 2] += p[r] * t.z;
        acc[r][4 * w + 3] += p[r] * t.w;
      }
    }
  }
#pragma unroll
  for (int r = 0; r < NR; ++r) {
    int row = tid + 128 * r;
    float inv = 1.f / l[r];
    float4* op = (float4*)(o + ((size_t)(b0 + bl) * S + row) * DMODEL + hc);
#pragma unroll
    for (int w = 0; w < 8; ++w) {
      float4 t;
      t.x = acc[r][4 * w] * inv;     t.y = acc[r][4 * w + 1] * inv;
      t.z = acc[r][4 * w + 2] * inv; t.w = acc[r][4 * w + 3] * inv;
      op[w] = t;
    }
  }
}

// ---------------- fused scoring (R1-proven) ----------------
__global__ __launch_bounds__(256) void k_score(
    const int* __restrict__ qids, const int* __restrict__ dids,
    const float* __restrict__ emb, const float* __restrict__ xq,
    const float* __restrict__ xd, const float* __restrict__ a_ptr,
    const float* __restrict__ mlp_w, float* __restrict__ out) {
  __shared__ float qmix[32 * 256];
  __shared__ float qks[32 * 11];
  __shared__ float qmask_s[32];
  int b = blockIdx.x, tid = threadIdx.x;
  float av = a_ptr[0], aw = 1.f - av;
  for (int q = 0; q < 32; ++q) {
    int qid = qids[b * 32 + q];
    float qm = qid > 0 ? 1.f : 0.f;
    float ev = emb[(size_t)qid * 256 + tid];
    float xv = xq[((size_t)b * 32 + q) * 256 + tid];
    qmix[q * 256 + tid] = (av * ev + aw * xv) * qm;
    if (tid == 0) qmask_s[q] = qm;
  }
  for (int i = tid; i < 352; i += 256) qks[i] = 0.f;
  __syncthreads();
  int j = tid;
  int did = dids[b * 256 + j];
  float dmask = did > 0 ? 1.f : 0.f;
  float sim[32];
#pragma unroll
  for (int q = 0; q < 32; ++q) sim[q] = 0.f;
  const float4* de = (const float4*)(emb + (size_t)did * 256);
  const float4* dxp = (const float4*)(xd + ((size_t)b * 256 + j) * 256);
  for (int c = 0; c < 4; ++c) {
    float4 dreg[16];
#pragma unroll
    for (int w = 0; w < 16; ++w) {
      float4 e = de[c * 16 + w], x = dxp[c * 16 + w];
      dreg[w].x = av * e.x + aw * x.x;
      dreg[w].y = av * e.y + aw * x.y;
      dreg[w].z = av * e.z + aw * x.z;
      dreg[w].w = av * e.w + aw * x.w;
    }
#pragma unroll
    for (int q = 0; q < 32; ++q) {
      const float4* qp = (const float4*)&qmix[q * 256 + c * 64];
      float d_ = 0.f;
#pragma unroll
      for (int w = 0; w < 16; ++w) {
        float4 t = qp[w];
        d_ += t.x * dreg[w].x + t.y * dreg[w].y + t.z * dreg[w].z + t.w * dreg[w].w;
      }
      sim[q] += d_;
    }
  }
  const float MU[11] = {1.f, 0.9f, 0.7f, 0.5f, 0.3f, 0.1f, -0.1f, -0.3f, -0.5f, -0.7f, -0.9f};
  const float IC[11] = {5e7f, 50.f, 50.f, 50.f, 50.f, 50.f, 50.f, 50.f, 50.f, 50.f, 50.f};
  for (int q = 0; q < 32; ++q) {
    float s = sim[q];
    float f = dmask * qmask_s[q];
#pragma unroll
    for (int k = 0; k < 11; ++k) {
      float d_ = s - MU[k];
      float v = expf(-d_ * d_ * IC[k]) * f;
#pragma unroll
      for (int o = 32; o > 0; o >>= 1) v += __shfl_xor(v, o);
      if ((tid & 63) == 0) atomicAdd(&qks[q * 11 + k], v);
    }
  }
  __syncthreads();
  if (tid < 32) {
    float qm = qmask_s[tid];
    float p = 0.f;
#pragma unroll
    for (int k = 0; k < 11; ++k) {
      float qv = qks[tid * 11 + k];
      p += mlp_w[k] * (qm * logf(fmaxf(qv, 1e-10f)) + qv * (1.f / 256.f));
    }
#pragma unroll
    for (int o = 16; o > 0; o >>= 1) p += __shfl_xor(p, o);
    if (tid == 0) out[b] = p;
  }
}

// ---------------- host-side encoder schedule ----------------
static void run_encoder(float* x, int S, int B, int CB, int FC,
    const float* Wqkv, const float* bqkv, const float* Wo, const float* bo,
    const float* l1s, const float* l1b, const float* W1, const float* b1,
    const float* W2, const float* b2, const float* l2s, const float* l2b,
    float* qkv, float* t0, float* h, hipStream_t stream) {
  int tokens = B * S;
  int nchunk = B / CB;
  for (int l = 0; l < 2; ++l) {
    const float* wq = Wqkv + (size_t)l * 768 * 256;
    const float* bq = bqkv + l * 768;
    const float* wo = Wo + (size_t)l * 256 * 256;
    const float* bo_ = bo + l * 256;
    const float* w1 = W1 + (size_t)l * 2048 * 256;
    const float* b1_ = b1 + l * 2048;
    const float* w2 = W2 + (size_t)l * 256 * 2048;
    const float* b2_ = b2 + l * 256;
    for (int c = 0; c < nchunk; ++c) {
      float* xc = x + (size_t)c * CB * S * 256;
      int Mc = CB * S;
      k_gemm<false><<<dim3(6, Mc / 128), 256, 0, stream>>>(xc, wq, bq, qkv, Mc, 768, 256);
      if (S == 256)
        k_attn<2><<<CB * 8, 128, 0, stream>>>(qkv, t0, S, c * CB);
      else
        k_attn<1><<<CB * 8, 128, 0, stream>>>(qkv, t0, S, c * CB);
    }
    // Wo + bias + residual + LN1, in-place into x
    k_gemm_ln<<<tokens / 64, 256, 0, stream>>>(t0, wo, bo_, x,
        l1s + l * 256, l1b + l * 256, tokens, 256);
    // FFN: W1+ReLU -> h ; W2 + bias + residual + LN2 in-place into x
    for (int f = 0; f < tokens; f += FC) {
      int Mc = (tokens - f < FC) ? (tokens - f) : FC;
      k_gemm<true><<<dim3(16, Mc / 128), 256, 0, stream>>>(x + (size_t)f * 256, w1, b1_, h, Mc, 2048, 256);
      k_gemm_ln<<<Mc / 64, 256, 0, stream>>>(h, w2, b2_, x + (size_t)f * 256,
          l2s + l * 256, l2b + l * 256, Mc, 2048);
    }
  }
}

extern "C" void kernel_launch(void* const* d_in, const int* in_sizes, int n_in,
                              void* d_out, int out_size, void* d_ws, size_t ws_size,
                              hipStream_t stream) {
  const int* qids = (const int*)d_in[0];
  const int* dids = (const int*)d_in[1];
  const float* emb = (const float*)d_in[2];
  const float* a = (const float*)d_in[3];
  const float* mlp_w = (const float*)d_in[4];
  const float* Wqkv = (const float*)d_in[5];
  const float* bqkv = (const float*)d_in[6];
  const float* Wo = (const float*)d_in[7];
  const float* bo = (const float*)d_in[8];
  const float* l1s = (const float*)d_in[9];
  const float* l1b = (const float*)d_in[10];
  const float* W1 = (const float*)d_in[11];
  const float* b1 = (const float*)d_in[12];
  const float* W2 = (const float*)d_in[13];
  const float* b2 = (const float*)d_in[14];
  const float* l2s = (const float*)d_in[15];
  const float* l2b = (const float*)d_in[16];
  float* out = (float*)d_out;
  float* ws = (float*)d_ws;

  size_t wsf = ws_size / 4;
  float* xq = ws;                    // 2,097,152
  float* xd = xq + 2097152;          // 16,777,216
  float* t0 = xd + 16777216;         // 16,777,216 (attn out)
  float* qkv = t0 + 16777216;        // CB*196608
  const size_t fixed = 2097152 + 2 * 16777216UL;

  const int cbs[] = {256, 256, 128, 64, 32, 16, 8};
  const int fcs[] = {65536, 32768, 32768, 16384, 8192, 4096, 2048};
  int CB = 8, FC = 2048;
  for (int i = 0; i < 7; ++i) {
    if (fixed + (size_t)cbs[i] * 196608 + (size_t)fcs[i] * 2048 <= wsf) {
      CB = cbs[i]; FC = fcs[i]; break;
    }
  }
  float* h = qkv + (size_t)CB * 196608;

  k_embed<<<256 * 32 / 4, 256, 0, stream>>>(qids, emb, xq, 32);
  k_embed<<<256 * 256 / 4, 256, 0, stream>>>(dids, emb, xd, 256);

  run_encoder(xd, 256, 256, CB, FC, Wqkv, bqkv, Wo, bo, l1s, l1b, W1, b1,
              W2, b2, l2s, l2b, qkv, t0, h, stream);
  int CBq = CB * 8; if (CBq > 256) CBq = 256;
  run_encoder(xq, 32, 256, CBq, FC, Wqkv, bqkv, Wo, bo, l1s, l1b, W1, b1,
              W2, b2, l2s, l2b, qkv, t0, h, stream);

  k_score<<<256, 256, 0, stream>>>(qids, dids, emb, xq, xd, a, mlp_w, out);
}

// Round 9
// 7185.487 us; speedup vs baseline: 2.5838x; 2.5838x over previous
//
#include <hip/hip_runtime.h>
#include <math.h>

// KNRM-style ranker, fp32 end-to-end (kernel-0 sigma=1e-4 makes sim
// precision-critical: bf16/MFMA would flip exp-window hits).
// R9 = R8 kernels (quadrant-read GEMM, fused Wo/W2+LN, merged embed/pe)
// with a FULLY ADAPTIVE workspace layout. R7/R8 crashed by hardcoding
// 680MB/360MB layouts; proven bounds are only ws in [233MB, 360MB).
// Layout: x(18.9M) + t0(18.9M) + pe(64K) + shared scratch
// (doc-QKV chunk | FFN h chunk | query QKV), sized by ladder from ws_size.

#define DMODEL 256
typedef float f32x4 __attribute__((ext_vector_type(4)));

// ---------------- positional-encoding table: pe[s][d], s<256 ----------------
__global__ __launch_bounds__(256) void k_pe(float* __restrict__ pe) {
  int s = blockIdx.x, d = threadIdx.x;
  int i2 = d & ~1;
  float freq = expf((float)i2 * (-9.210340371976184f / 256.f));
  float ang = (float)s * freq;
  pe[s * 256 + d] = (d & 1) ? cosf(ang) : sinf(ang);
}

// ---------------- embed (doc+query merged), 4 tokens / 256-thr block --------
__global__ __launch_bounds__(256) void k_embed(const int* __restrict__ dids,
    const int* __restrict__ qids, const float* __restrict__ emb,
    const float* __restrict__ pe, float* __restrict__ out_x) {
  int tid = threadIdx.x;
  int tok = blockIdx.x * 4 + (tid >> 6);
  int lane = tid & 63;
  int d0 = lane * 4;
  int id, s;
  if (tok < 65536) { id = dids[tok]; s = tok & 255; }
  else             { id = qids[tok - 65536]; s = (tok - 65536) & 31; }
  float m = id > 0 ? 2.f : 0.f;
  float4 e = *(const float4*)(emb + (size_t)id * DMODEL + d0);
  float4 p = *(const float4*)(pe + s * 256 + d0);
  float4 o;
  o.x = m * e.x + p.x; o.y = m * e.y + p.y;
  o.z = m * e.z + p.z; o.w = m * e.w + p.w;
  *(float4*)(out_x + (size_t)tok * DMODEL + d0) = o;
}

// ---------------- fp32 GEMM: out[M,N] = X[M,K] @ W[N,K]^T + bias ------------
// 128x128x16 tile, 256 threads, R5 ping-pong staging.
// READ mapping: wave wv owns quadrant rows (wv&1)*64.., cols (wv>>1)*64..;
// lane: r8=lane>>3 rows r8*4+{0..3}(+32), c8=lane&7 cols c8*4+{0..3}(+32).
// A/B reads: 8 distinct addrs x 16B -> banks 0..31 exactly once per half-wave.
template<bool RELU>
__global__ __launch_bounds__(256) void k_gemm(const float* __restrict__ X,
    const float* __restrict__ W, const float* __restrict__ bias,
    float* __restrict__ out, int M, int N, int K) {
  __shared__ float As[2][16][128];
  __shared__ float Bs[2][16][128];
  int n0 = blockIdx.x * 128;
  int m0 = blockIdx.y * 128;
  int tid = threadIdx.x;
  const int wv = tid >> 6, lane = tid & 63;
  const int r8 = lane >> 3, c8 = lane & 7;
  const int R0 = (wv & 1) * 64 + r8 * 4;
  const int C0 = (wv >> 1) * 64 + c8 * 4;
  int lr = tid >> 1;
  int lk = (tid & 1) << 3;
  const float* Xp = X + (size_t)(m0 + lr) * K + lk;
  const float* Wp = W + (size_t)(n0 + lr) * K + lk;

  float acc[8][8];
#pragma unroll
  for (int i = 0; i < 8; ++i)
#pragma unroll
    for (int j = 0; j < 8; ++j) acc[i][j] = 0.f;

  float4 a0, a1, b0, b1;

#define GLOADT(KT) do { \
    a0 = *(const float4*)(Xp + (KT)); a1 = *(const float4*)(Xp + (KT) + 4); \
    b0 = *(const float4*)(Wp + (KT)); b1 = *(const float4*)(Wp + (KT) + 4); } while (0)

#define LWRITE(BUF) do { \
    As[BUF][lk + 0][lr] = a0.x; As[BUF][lk + 1][lr] = a0.y; \
    As[BUF][lk + 2][lr] = a0.z; As[BUF][lk + 3][lr] = a0.w; \
    As[BUF][lk + 4][lr] = a1.x; As[BUF][lk + 5][lr] = a1.y; \
    As[BUF][lk + 6][lr] = a1.z; As[BUF][lk + 7][lr] = a1.w; \
    Bs[BUF][lk + 0][lr] = b0.x; Bs[BUF][lk + 1][lr] = b0.y; \
    Bs[BUF][lk + 2][lr] = b0.z; Bs[BUF][lk + 3][lr] = b0.w; \
    Bs[BUF][lk + 4][lr] = b1.x; Bs[BUF][lk + 5][lr] = b1.y; \
    Bs[BUF][lk + 6][lr] = b1.z; Bs[BUF][lk + 7][lr] = b1.w; } while (0)

#define COMPT(BUF) do { \
    _Pragma("unroll") \
    for (int k = 0; k < 16; ++k) { \
      float av[8], bv[8]; \
      *(float4*)&av[0] = *(const float4*)&As[BUF][k][R0]; \
      *(float4*)&av[4] = *(const float4*)&As[BUF][k][R0 + 32]; \
      *(float4*)&bv[0] = *(const float4*)&Bs[BUF][k][C0]; \
      *(float4*)&bv[4] = *(const float4*)&Bs[BUF][k][C0 + 32]; \
      _Pragma("unroll") \
      for (int i = 0; i < 8; ++i) \
        _Pragma("unroll") \
        for (int j = 0; j < 8; ++j) \
          acc[i][j] += av[i] * bv[j]; \
    } } while (0)

  const int nt = K >> 4;  // 16 or 128: even
  GLOADT(0);
  LWRITE(0);
  __syncthreads();
  for (int t = 0; t < nt; t += 2) {
    int k1 = (t + 1) * 16;
    GLOADT(k1);
    COMPT(0);
    LWRITE(1);
    __syncthreads();
    if (t + 2 < nt) {
      int k2 = (t + 2) * 16;
      GLOADT(k2);
      COMPT(1);
      LWRITE(0);
    } else {
      COMPT(1);
    }
    __syncthreads();
  }
#undef GLOADT
#undef LWRITE
#undef COMPT

#pragma unroll
  for (int i = 0; i < 8; ++i) {
    int mr = m0 + (wv & 1) * 64 + ((i < 4) ? (r8 * 4 + i) : (32 + r8 * 4 + i - 4));
#pragma unroll
    for (int jb = 0; jb < 2; ++jb) {
      int nc = n0 + (wv >> 1) * 64 + jb * 32 + c8 * 4;
      float4 bz = *(const float4*)(bias + nc);
      float4 o4;
      o4.x = acc[i][jb * 4 + 0] + bz.x;
      o4.y = acc[i][jb * 4 + 1] + bz.y;
      o4.z = acc[i][jb * 4 + 2] + bz.z;
      o4.w = acc[i][jb * 4 + 3] + bz.w;
      if (RELU) {
        o4.x = fmaxf(o4.x, 0.f); o4.y = fmaxf(o4.y, 0.f);
        o4.z = fmaxf(o4.z, 0.f); o4.w = fmaxf(o4.w, 0.f);
      }
      *(float4*)(out + (size_t)mr * N + nc) = o4;
    }
  }
}

// ---------------- GEMM (N=256) fused bias+residual+LayerNorm (R5 verbatim) --
__global__ __launch_bounds__(256) void k_gemm_ln(const float* __restrict__ X,
    const float* __restrict__ W, const float* __restrict__ bias,
    float* __restrict__ xres, const float* __restrict__ lns,
    const float* __restrict__ lnb, int M, int K) {
  __shared__ float As[2][16][64];
  __shared__ float Bs[2][16][256];
  const int tid = threadIdx.x;
  const int m0 = blockIdx.x * 64;
  const int tx = tid & 15, ty = tid >> 4;
  const int rowA = tid & 63;
  const int kqA = (tid >> 6) << 2;
  const float* Xp = X + (size_t)(m0 + rowA) * K + kqA;
  const float* Wp = W + (size_t)tid * K;

  f32x4 acc[4][4];
#pragma unroll
  for (int r = 0; r < 4; ++r)
#pragma unroll
    for (int q = 0; q < 4; ++q) acc[r][q] = 0.f;

  f32x4 a, b0, b1, b2, b3;

#define GL(KT) do { \
    a  = *(const f32x4*)(Xp + (KT)); \
    b0 = *(const f32x4*)(Wp + (KT));      b1 = *(const f32x4*)(Wp + (KT) + 4); \
    b2 = *(const f32x4*)(Wp + (KT) + 8);  b3 = *(const f32x4*)(Wp + (KT) + 12); } while (0)

#define LW(BUF) do { \
    As[BUF][kqA + 0][rowA] = a[0]; As[BUF][kqA + 1][rowA] = a[1]; \
    As[BUF][kqA + 2][rowA] = a[2]; As[BUF][kqA + 3][rowA] = a[3]; \
    Bs[BUF][ 0][tid] = b0[0]; Bs[BUF][ 1][tid] = b0[1]; \
    Bs[BUF][ 2][tid] = b0[2]; Bs[BUF][ 3][tid] = b0[3]; \
    Bs[BUF][ 4][tid] = b1[0]; Bs[BUF][ 5][tid] = b1[1]; \
    Bs[BUF][ 6][tid] = b1[2]; Bs[BUF][ 7][tid] = b1[3]; \
    Bs[BUF][ 8][tid] = b2[0]; Bs[BUF][ 9][tid] = b2[1]; \
    Bs[BUF][10][tid] = b2[2]; Bs[BUF][11][tid] = b2[3]; \
    Bs[BUF][12][tid] = b3[0]; Bs[BUF][13][tid] = b3[1]; \
    Bs[BUF][14][tid] = b3[2]; Bs[BUF][15][tid] = b3[3]; } while (0)

#define CP(BUF) do { \
    _Pragma("unroll") \
    for (int k = 0; k < 16; ++k) { \
      f32x4 av = *(const f32x4*)&As[BUF][k][ty * 4]; \
      f32x4 bv0 = *(const f32x4*)&Bs[BUF][k][tx * 4]; \
      f32x4 bv1 = *(const f32x4*)&Bs[BUF][k][64 + tx * 4]; \
      f32x4 bv2 = *(const f32x4*)&Bs[BUF][k][128 + tx * 4]; \
      f32x4 bv3 = *(const f32x4*)&Bs[BUF][k][192 + tx * 4]; \
      _Pragma("unroll") \
      for (int r = 0; r < 4; ++r) { \
        acc[r][0] += av[r] * bv0; acc[r][1] += av[r] * bv1; \
        acc[r][2] += av[r] * bv2; acc[r][3] += av[r] * bv3; \
      } \
    } } while (0)

  const int nt = K >> 4;  // 16 (Wo) or 128 (W2): even
  GL(0);
  LW(0);
  __syncthreads();
  for (int t = 0; t < nt; t += 2) {
    GL((t + 1) * 16);
    CP(0);
    LW(1);
    __syncthreads();
    if (t + 2 < nt) {
      GL((t + 2) * 16);
      CP(1);
      LW(0);
    } else {
      CP(1);
    }
    __syncthreads();
  }
#undef GL
#undef LW
#undef CP

  f32x4 bza[4], sca[4], lba[4];
#pragma unroll
  for (int q = 0; q < 4; ++q) {
    int c = q * 64 + tx * 4;
    bza[q] = *(const f32x4*)(bias + c);
    sca[q] = *(const f32x4*)(lns + c);
    lba[q] = *(const f32x4*)(lnb + c);
  }
#pragma unroll
  for (int r = 0; r < 4; ++r) {
    size_t row = (size_t)m0 + ty * 4 + r;
    f32x4 v[4];
    float ps = 0.f;
#pragma unroll
    for (int q = 0; q < 4; ++q) {
      f32x4 xr = *(const f32x4*)(xres + row * 256 + q * 64 + tx * 4);
      v[q] = acc[r][q] + bza[q] + xr;
      ps += v[q][0] + v[q][1] + v[q][2] + v[q][3];
    }
    ps += __shfl_xor(ps, 1); ps += __shfl_xor(ps, 2);
    ps += __shfl_xor(ps, 4); ps += __shfl_xor(ps, 8);
    float mean = ps * (1.f / 256.f);
    float ss = 0.f;
#pragma unroll
    for (int q = 0; q < 4; ++q) {
      v[q] -= mean;
      ss += v[q][0] * v[q][0] + v[q][1] * v[q][1]
          + v[q][2] * v[q][2] + v[q][3] * v[q][3];
    }
    ss += __shfl_xor(ss, 1); ss += __shfl_xor(ss, 2);
    ss += __shfl_xor(ss, 4); ss += __shfl_xor(ss, 8);
    float rs = rsqrtf(ss * (1.f / 256.f) + 1e-5f);
#pragma unroll
    for (int q = 0; q < 4; ++q) {
      f32x4 y = v[q] * rs * sca[q] + lba[q];
      *(f32x4*)(xres + row * 256 + q * 64 + tx * 4) = y;
    }
  }
}

// ---------------- fused attention (R5 verbatim) ----------------
template<int NR>
__global__ __launch_bounds__(128) void k_attn(const float* __restrict__ qkv,
    float* __restrict__ o, int S, int b0) {
  __shared__ float Ks[256 * 32];
  __shared__ float Vs[256 * 32];
  int bl = blockIdx.x >> 3;
  int h = blockIdx.x & 7;
  int tid = threadIdx.x;
  const float* base = qkv + (size_t)bl * S * 768;
  int hc = h * 32;
  for (int f = tid; f < S * 32; f += 128) {
    int s = f >> 5, e = f & 31;
    Ks[f] = base[(size_t)s * 768 + 256 + hc + e];
    Vs[f] = base[(size_t)s * 768 + 512 + hc + e];
  }
  __syncthreads();
  if (tid >= S) return;
  const float scale = 0.17677669529663687f;
  float q[NR][32], acc[NR][32], m[NR], l[NR];
#pragma unroll
  for (int r = 0; r < NR; ++r) {
    int row = tid + 128 * r;
    const float4* qp = (const float4*)(base + (size_t)row * 768 + hc);
#pragma unroll
    for (int w = 0; w < 8; ++w) {
      float4 t = qp[w];
      q[r][4 * w] = t.x; q[r][4 * w + 1] = t.y; q[r][4 * w + 2] = t.z; q[r][4 * w + 3] = t.w;
    }
    m[r] = -1e30f; l[r] = 0.f;
#pragma unroll
    for (int e = 0; e < 32; ++e) acc[r][e] = 0.f;
  }
  for (int j = 0; j < S; ++j) {
    float kv[32];
    const float4* kp = (const float4*)&Ks[j * 32];
#pragma unroll
    for (int w = 0; w < 8; ++w) {
      float4 t = kp[w];
      kv[4 * w] = t.x; kv[4 * w + 1] = t.y; kv[4 * w + 2] = t.z; kv[4 * w + 3] = t.w;
    }
    float p[NR];
#pragma unroll
    for (int r = 0; r < NR; ++r) {
      float dot = 0.f;
#pragma unroll
      for (int e = 0; e < 32; ++e) dot += q[r][e] * kv[e];
      float s_ = dot * scale;
      float mn = fmaxf(m[r], s_);
      p[r] = __expf(s_ - mn);
      if (mn > m[r]) {
        float al = __expf(m[r] - mn);
        l[r] *= al;
#pragma unroll
        for (int e = 0; e < 32; ++e) acc[r][e] *= al;
        m[r] = mn;
      }
      l[r] += p[r];
    }
    const float4* vp = (const float4*)&Vs[j * 32];
#pragma unroll
    for (int w = 0; w < 8; ++w) {
      float4 t = vp[w];
#pragma unroll
      for (int r = 0; r < NR; ++r) {
        acc[r][4 * w]     += p[r] * t.x;
        acc[r][4 * w + 1] += p[r] * t.y;
        acc[r][4 * w + 2] += p[r] * t.z;
        acc[r][4 * w + 3] += p[r] * t.w;
      }
    }
  }
#pragma unroll
  for (int r = 0; r < NR; ++r) {
    int row = tid + 128 * r;
    float inv = 1.f / l[r];
    float4* op = (float4*)(o + ((size_t)(b0 + bl) * S + row) * DMODEL + hc);
#pragma unroll
    for (int w = 0; w < 8; ++w) {
      float4 t;
      t.x = acc[r][4 * w] * inv;     t.y = acc[r][4 * w + 1] * inv;
      t.z = acc[r][4 * w + 2] * inv; t.w = acc[r][4 * w + 3] * inv;
      op[w] = t;
    }
  }
}

// ---------------- fused scoring (R5 verbatim) ----------------
__global__ __launch_bounds__(256) void k_score(
    const int* __restrict__ qids, const int* __restrict__ dids,
    const float* __restrict__ emb, const float* __restrict__ xq,
    const float* __restrict__ xd, const float* __restrict__ a_ptr,
    const float* __restrict__ mlp_w, float* __restrict__ out) {
  __shared__ float qmix[32 * 256];
  __shared__ float qks[32 * 11];
  __shared__ float qmask_s[32];
  int b = blockIdx.x, tid = threadIdx.x;
  float av = a_ptr[0], aw = 1.f - av;
  for (int q = 0; q < 32; ++q) {
    int qid = qids[b * 32 + q];
    float qm = qid > 0 ? 1.f : 0.f;
    float ev = emb[(size_t)qid * 256 + tid];
    float xv = xq[((size_t)b * 32 + q) * 256 + tid];
    qmix[q * 256 + tid] = (av * ev + aw * xv) * qm;
    if (tid == 0) qmask_s[q] = qm;
  }
  for (int i = tid; i < 352; i += 256) qks[i] = 0.f;
  __syncthreads();
  int j = tid;
  int did = dids[b * 256 + j];
  float dmask = did > 0 ? 1.f : 0.f;
  float sim[32];
#pragma unroll
  for (int q = 0; q < 32; ++q) sim[q] = 0.f;
  const float4* de = (const float4*)(emb + (size_t)did * 256);
  const float4* dxp = (const float4*)(xd + ((size_t)b * 256 + j) * 256);
  for (int c = 0; c < 4; ++c) {
    float4 dreg[16];
#pragma unroll
    for (int w = 0; w < 16; ++w) {
      float4 e = de[c * 16 + w], x = dxp[c * 16 + w];
      dreg[w].x = av * e.x + aw * x.x;
      dreg[w].y = av * e.y + aw * x.y;
      dreg[w].z = av * e.z + aw * x.z;
      dreg[w].w = av * e.w + aw * x.w;
    }
#pragma unroll
    for (int q = 0; q < 32; ++q) {
      const float4* qp = (const float4*)&qmix[q * 256 + c * 64];
      float d_ = 0.f;
#pragma unroll
      for (int w = 0; w < 16; ++w) {
        float4 t = qp[w];
        d_ += t.x * dreg[w].x + t.y * dreg[w].y + t.z * dreg[w].z + t.w * dreg[w].w;
      }
      sim[q] += d_;
    }
  }
  const float MU[11] = {1.f, 0.9f, 0.7f, 0.5f, 0.3f, 0.1f, -0.1f, -0.3f, -0.5f, -0.7f, -0.9f};
  const float IC[11] = {5e7f, 50.f, 50.f, 50.f, 50.f, 50.f, 50.f, 50.f, 50.f, 50.f, 50.f};
  for (int q = 0; q < 32; ++q) {
    float s = sim[q];
    float f = dmask * qmask_s[q];
#pragma unroll
    for (int k = 0; k < 11; ++k) {
      float d_ = s - MU[k];
      float v = expf(-d_ * d_ * IC[k]) * f;
#pragma unroll
      for (int o = 32; o > 0; o >>= 1) v += __shfl_xor(v, o);
      if ((tid & 63) == 0) atomicAdd(&qks[q * 11 + k], v);
    }
  }
  __syncthreads();
  if (tid < 32) {
    float qm = qmask_s[tid];
    float p = 0.f;
#pragma unroll
    for (int k = 0; k < 11; ++k) {
      float qv = qks[tid * 11 + k];
      p += mlp_w[k] * (qm * logf(fmaxf(qv, 1e-10f)) + qv * (1.f / 256.f));
    }
#pragma unroll
    for (int o = 16; o > 0; o >>= 1) p += __shfl_xor(p, o);
    if (tid == 0) out[b] = p;
  }
}

extern "C" void kernel_launch(void* const* d_in, const int* in_sizes, int n_in,
                              void* d_out, int out_size, void* d_ws, size_t ws_size,
                              hipStream_t stream) {
  const int* qids = (const int*)d_in[0];
  const int* dids = (const int*)d_in[1];
  const float* emb = (const float*)d_in[2];
  const float* a = (const float*)d_in[3];
  const float* mlp_w = (const float*)d_in[4];
  const float* Wqkv = (const float*)d_in[5];
  const float* bqkv = (const float*)d_in[6];
  const float* Wo = (const float*)d_in[7];
  const float* bo = (const float*)d_in[8];
  const float* l1s = (const float*)d_in[9];
  const float* l1b = (const float*)d_in[10];
  const float* W1 = (const float*)d_in[11];
  const float* b1 = (const float*)d_in[12];
  const float* W2 = (const float*)d_in[13];
  const float* b2 = (const float*)d_in[14];
  const float* l2s = (const float*)d_in[15];
  const float* l2b = (const float*)d_in[16];
  float* out = (float*)d_out;
  float* ws = (float*)d_ws;

  const int TOK = 73728;                    // 65536 doc + 8192 query tokens
  const size_t QRY_QKV = (size_t)8192 * 768;  // 6,291,456 floats

  size_t wsf = ws_size / 4;
  // mandatory: x (TOK*256) + t0 (TOK*256) + pe (65536)
  const size_t fixed = 2 * (size_t)TOK * 256 + 65536;
  // ladder: (CB doc-batches per QKV chunk, FC FFN tokens per chunk)
  const int cbs[] = {256, 128, 64, 32, 16, 8};
  const int fcs[] = {24576, 12288, 9216, 6144, 3072, 2048};
  int CB = 8, FC = 2048;
  for (int i = 0; i < 6; ++i) {
    size_t sc = (size_t)cbs[i] * 196608;            // doc QKV chunk
    size_t s2 = (size_t)fcs[i] * 2048;              // FFN h chunk
    size_t scr = sc > s2 ? sc : s2;
    if (scr < QRY_QKV) scr = QRY_QKV;
    if (fixed + scr <= wsf) { CB = cbs[i]; FC = fcs[i]; break; }
  }
  size_t scrN = (size_t)CB * 196608;
  { size_t s2 = (size_t)FC * 2048; if (s2 > scrN) scrN = s2; if (QRY_QKV > scrN) scrN = QRY_QKV; }

  float* x       = ws;                          // 18,874,368
  float* t0      = x + (size_t)TOK * 256;       // 18,874,368
  float* pe      = t0 + (size_t)TOK * 256;      // 65,536
  float* scratch = pe + 65536;                  // scrN floats (qkv | h)

  k_pe<<<256, 256, 0, stream>>>(pe);
  k_embed<<<TOK / 4, 256, 0, stream>>>(dids, qids, emb, pe, x);

  for (int l = 0; l < 2; ++l) {
    const float* wq = Wqkv + (size_t)l * 768 * 256;
    const float* bq = bqkv + l * 768;
    const float* wo = Wo + (size_t)l * 256 * 256;
    const float* bo_ = bo + l * 256;
    const float* w1 = W1 + (size_t)l * 2048 * 256;
    const float* b1_ = b1 + l * 2048;
    const float* w2 = W2 + (size_t)l * 256 * 2048;
    const float* b2_ = b2 + l * 256;

    // doc QKV + attention, chunked by CB batches (CB*256 tokens)
    for (int c = 0; c < 256; c += CB) {
      int Mc = CB * 256;
      k_gemm<false><<<dim3(6, Mc / 128), 256, 0, stream>>>(
          x + (size_t)c * 65536, wq, bq, scratch, Mc, 768, 256);
      k_attn<2><<<CB * 8, 128, 0, stream>>>(scratch, t0, 256, c);
    }
    // query QKV + attention (single chunk: 8192 tokens)
    k_gemm<false><<<dim3(6, 64), 256, 0, stream>>>(
        x + (size_t)65536 * 256, wq, bq, scratch, 8192, 768, 256);
    k_attn<1><<<256 * 8, 128, 0, stream>>>(scratch, t0 + (size_t)65536 * 256, 32, 0);
    // Wo + bias + residual + LN1 over all tokens, in-place into x
    k_gemm_ln<<<TOK / 64, 256, 0, stream>>>(t0, wo, bo_, x,
        l1s + l * 256, l1b + l * 256, TOK, 256);
    // FFN in chunks of FC tokens (FC divides 73728 for all ladder entries)
    for (int f = 0; f < TOK; f += FC) {
      k_gemm<true><<<dim3(16, FC / 128), 256, 0, stream>>>(
          x + (size_t)f * 256, w1, b1_, scratch, FC, 2048, 256);
      k_gemm_ln<<<FC / 64, 256, 0, stream>>>(scratch, w2, b2_, x + (size_t)f * 256,
          l2s + l * 256, l2b + l * 256, FC, 2048);
    }
  }

  k_score<<<256, 256, 0, stream>>>(qids, dids, emb, x + (size_t)65536 * 256,
                                   x, a, mlp_w, out);
}

// Round 10
// 6844.206 us; speedup vs baseline: 2.7127x; 1.0499x over previous
//
#include <hip/hip_runtime.h>
#include <math.h>

// KNRM-style ranker, fp32 end-to-end (kernel-0 sigma=1e-4 makes sim
// precision-critical: bf16/MFMA would flip exp-window hits).
// R10 vs R9 (7.19ms): attention rewritten, all else verbatim R9.
//  - doc attn: 256 thr/block (1 q-row/thread), K/V 64KB LDS, dot as two
//    independent f32x4 chains -> 2 waves/SIMD occupancy + shorter dep chain
//    (R9: 128 thr, scalar 32-deep dot chain, 1 wave/SIMD, VALUBusy 45%).
//  - query attn: block=batch, 256 thr=(head,row), all lanes active
//    (R9 left 96/128 idle).
// GEMMs (quadrant-read), Wo/W2+LN fusion, adaptive ws layout: unchanged.

#define DMODEL 256
typedef float f32x4 __attribute__((ext_vector_type(4)));

// ---------------- positional-encoding table: pe[s][d], s<256 ----------------
__global__ __launch_bounds__(256) void k_pe(float* __restrict__ pe) {
  int s = blockIdx.x, d = threadIdx.x;
  int i2 = d & ~1;
  float freq = expf((float)i2 * (-9.210340371976184f / 256.f));
  float ang = (float)s * freq;
  pe[s * 256 + d] = (d & 1) ? cosf(ang) : sinf(ang);
}

// ---------------- embed (doc+query merged), 4 tokens / 256-thr block --------
__global__ __launch_bounds__(256) void k_embed(const int* __restrict__ dids,
    const int* __restrict__ qids, const float* __restrict__ emb,
    const float* __restrict__ pe, float* __restrict__ out_x) {
  int tid = threadIdx.x;
  int tok = blockIdx.x * 4 + (tid >> 6);
  int lane = tid & 63;
  int d0 = lane * 4;
  int id, s;
  if (tok < 65536) { id = dids[tok]; s = tok & 255; }
  else             { id = qids[tok - 65536]; s = (tok - 65536) & 31; }
  float m = id > 0 ? 2.f : 0.f;
  float4 e = *(const float4*)(emb + (size_t)id * DMODEL + d0);
  float4 p = *(const float4*)(pe + s * 256 + d0);
  float4 o;
  o.x = m * e.x + p.x; o.y = m * e.y + p.y;
  o.z = m * e.z + p.z; o.w = m * e.w + p.w;
  *(float4*)(out_x + (size_t)tok * DMODEL + d0) = o;
}

// ---------------- fp32 GEMM: out[M,N] = X[M,K] @ W[N,K]^T + bias ------------
// 128x128x16 tile, 256 threads, ping-pong staging, wave-quadrant reads.
template<bool RELU>
__global__ __launch_bounds__(256) void k_gemm(const float* __restrict__ X,
    const float* __restrict__ W, const float* __restrict__ bias,
    float* __restrict__ out, int M, int N, int K) {
  __shared__ float As[2][16][128];
  __shared__ float Bs[2][16][128];
  int n0 = blockIdx.x * 128;
  int m0 = blockIdx.y * 128;
  int tid = threadIdx.x;
  const int wv = tid >> 6, lane = tid & 63;
  const int r8 = lane >> 3, c8 = lane & 7;
  const int R0 = (wv & 1) * 64 + r8 * 4;
  const int C0 = (wv >> 1) * 64 + c8 * 4;
  int lr = tid >> 1;
  int lk = (tid & 1) << 3;
  const float* Xp = X + (size_t)(m0 + lr) * K + lk;
  const float* Wp = W + (size_t)(n0 + lr) * K + lk;

  float acc[8][8];
#pragma unroll
  for (int i = 0; i < 8; ++i)
#pragma unroll
    for (int j = 0; j < 8; ++j) acc[i][j] = 0.f;

  float4 a0, a1, b0, b1;

#define GLOADT(KT) do { \
    a0 = *(const float4*)(Xp + (KT)); a1 = *(const float4*)(Xp + (KT) + 4); \
    b0 = *(const float4*)(Wp + (KT)); b1 = *(const float4*)(Wp + (KT) + 4); } while (0)

#define LWRITE(BUF) do { \
    As[BUF][lk + 0][lr] = a0.x; As[BUF][lk + 1][lr] = a0.y; \
    As[BUF][lk + 2][lr] = a0.z; As[BUF][lk + 3][lr] = a0.w; \
    As[BUF][lk + 4][lr] = a1.x; As[BUF][lk + 5][lr] = a1.y; \
    As[BUF][lk + 6][lr] = a1.z; As[BUF][lk + 7][lr] = a1.w; \
    Bs[BUF][lk + 0][lr] = b0.x; Bs[BUF][lk + 1][lr] = b0.y; \
    Bs[BUF][lk + 2][lr] = b0.z; Bs[BUF][lk + 3][lr] = b0.w; \
    Bs[BUF][lk + 4][lr] = b1.x; Bs[BUF][lk + 5][lr] = b1.y; \
    Bs[BUF][lk + 6][lr] = b1.z; Bs[BUF][lk + 7][lr] = b1.w; } while (0)

#define COMPT(BUF) do { \
    _Pragma("unroll") \
    for (int k = 0; k < 16; ++k) { \
      float av[8], bv[8]; \
      *(float4*)&av[0] = *(const float4*)&As[BUF][k][R0]; \
      *(float4*)&av[4] = *(const float4*)&As[BUF][k][R0 + 32]; \
      *(float4*)&bv[0] = *(const float4*)&Bs[BUF][k][C0]; \
      *(float4*)&bv[4] = *(const float4*)&Bs[BUF][k][C0 + 32]; \
      _Pragma("unroll") \
      for (int i = 0; i < 8; ++i) \
        _Pragma("unroll") \
        for (int j = 0; j < 8; ++j) \
          acc[i][j] += av[i] * bv[j]; \
    } } while (0)

  const int nt = K >> 4;  // 16 or 128: even
  GLOADT(0);
  LWRITE(0);
  __syncthreads();
  for (int t = 0; t < nt; t += 2) {
    int k1 = (t + 1) * 16;
    GLOADT(k1);
    COMPT(0);
    LWRITE(1);
    __syncthreads();
    if (t + 2 < nt) {
      int k2 = (t + 2) * 16;
      GLOADT(k2);
      COMPT(1);
      LWRITE(0);
    } else {
      COMPT(1);
    }
    __syncthreads();
  }
#undef GLOADT
#undef LWRITE
#undef COMPT

#pragma unroll
  for (int i = 0; i < 8; ++i) {
    int mr = m0 + (wv & 1) * 64 + ((i < 4) ? (r8 * 4 + i) : (32 + r8 * 4 + i - 4));
#pragma unroll
    for (int jb = 0; jb < 2; ++jb) {
      int nc = n0 + (wv >> 1) * 64 + jb * 32 + c8 * 4;
      float4 bz = *(const float4*)(bias + nc);
      float4 o4;
      o4.x = acc[i][jb * 4 + 0] + bz.x;
      o4.y = acc[i][jb * 4 + 1] + bz.y;
      o4.z = acc[i][jb * 4 + 2] + bz.z;
      o4.w = acc[i][jb * 4 + 3] + bz.w;
      if (RELU) {
        o4.x = fmaxf(o4.x, 0.f); o4.y = fmaxf(o4.y, 0.f);
        o4.z = fmaxf(o4.z, 0.f); o4.w = fmaxf(o4.w, 0.f);
      }
      *(float4*)(out + (size_t)mr * N + nc) = o4;
    }
  }
}

// ---------------- GEMM (N=256) fused bias+residual+LayerNorm ----------------
__global__ __launch_bounds__(256) void k_gemm_ln(const float* __restrict__ X,
    const float* __restrict__ W, const float* __restrict__ bias,
    float* __restrict__ xres, const float* __restrict__ lns,
    const float* __restrict__ lnb, int M, int K) {
  __shared__ float As[2][16][64];
  __shared__ float Bs[2][16][256];
  const int tid = threadIdx.x;
  const int m0 = blockIdx.x * 64;
  const int tx = tid & 15, ty = tid >> 4;
  const int rowA = tid & 63;
  const int kqA = (tid >> 6) << 2;
  const float* Xp = X + (size_t)(m0 + rowA) * K + kqA;
  const float* Wp = W + (size_t)tid * K;

  f32x4 acc[4][4];
#pragma unroll
  for (int r = 0; r < 4; ++r)
#pragma unroll
    for (int q = 0; q < 4; ++q) acc[r][q] = 0.f;

  f32x4 a, b0, b1, b2, b3;

#define GL(KT) do { \
    a  = *(const f32x4*)(Xp + (KT)); \
    b0 = *(const f32x4*)(Wp + (KT));      b1 = *(const f32x4*)(Wp + (KT) + 4); \
    b2 = *(const f32x4*)(Wp + (KT) + 8);  b3 = *(const f32x4*)(Wp + (KT) + 12); } while (0)

#define LW(BUF) do { \
    As[BUF][kqA + 0][rowA] = a[0]; As[BUF][kqA + 1][rowA] = a[1]; \
    As[BUF][kqA + 2][rowA] = a[2]; As[BUF][kqA + 3][rowA] = a[3]; \
    Bs[BUF][ 0][tid] = b0[0]; Bs[BUF][ 1][tid] = b0[1]; \
    Bs[BUF][ 2][tid] = b0[2]; Bs[BUF][ 3][tid] = b0[3]; \
    Bs[BUF][ 4][tid] = b1[0]; Bs[BUF][ 5][tid] = b1[1]; \
    Bs[BUF][ 6][tid] = b1[2]; Bs[BUF][ 7][tid] = b1[3]; \
    Bs[BUF][ 8][tid] = b2[0]; Bs[BUF][ 9][tid] = b2[1]; \
    Bs[BUF][10][tid] = b2[2]; Bs[BUF][11][tid] = b2[3]; \
    Bs[BUF][12][tid] = b3[0]; Bs[BUF][13][tid] = b3[1]; \
    Bs[BUF][14][tid] = b3[2]; Bs[BUF][15][tid] = b3[3]; } while (0)

#define CP(BUF) do { \
    _Pragma("unroll") \
    for (int k = 0; k < 16; ++k) { \
      f32x4 av = *(const f32x4*)&As[BUF][k][ty * 4]; \
      f32x4 bv0 = *(const f32x4*)&Bs[BUF][k][tx * 4]; \
      f32x4 bv1 = *(const f32x4*)&Bs[BUF][k][64 + tx * 4]; \
      f32x4 bv2 = *(const f32x4*)&Bs[BUF][k][128 + tx * 4]; \
      f32x4 bv3 = *(const f32x4*)&Bs[BUF][k][192 + tx * 4]; \
      _Pragma("unroll") \
      for (int r = 0; r < 4; ++r) { \
        acc[r][0] += av[r] * bv0; acc[r][1] += av[r] * bv1; \
        acc[r][2] += av[r] * bv2; acc[r][3] += av[r] * bv3; \
      } \
    } } while (0)

  const int nt = K >> 4;  // 16 (Wo) or 128 (W2): even
  GL(0);
  LW(0);
  __syncthreads();
  for (int t = 0; t < nt; t += 2) {
    GL((t + 1) * 16);
    CP(0);
    LW(1);
    __syncthreads();
    if (t + 2 < nt) {
      GL((t + 2) * 16);
      CP(1);
      LW(0);
    } else {
      CP(1);
    }
    __syncthreads();
  }
#undef GL
#undef LW
#undef CP

  f32x4 bza[4], sca[4], lba[4];
#pragma unroll
  for (int q = 0; q < 4; ++q) {
    int c = q * 64 + tx * 4;
    bza[q] = *(const f32x4*)(bias + c);
    sca[q] = *(const f32x4*)(lns + c);
    lba[q] = *(const f32x4*)(lnb + c);
  }
#pragma unroll
  for (int r = 0; r < 4; ++r) {
    size_t row = (size_t)m0 + ty * 4 + r;
    f32x4 v[4];
    float ps = 0.f;
#pragma unroll
    for (int q = 0; q < 4; ++q) {
      f32x4 xr = *(const f32x4*)(xres + row * 256 + q * 64 + tx * 4);
      v[q] = acc[r][q] + bza[q] + xr;
      ps += v[q][0] + v[q][1] + v[q][2] + v[q][3];
    }
    ps += __shfl_xor(ps, 1); ps += __shfl_xor(ps, 2);
    ps += __shfl_xor(ps, 4); ps += __shfl_xor(ps, 8);
    float mean = ps * (1.f / 256.f);
    float ss = 0.f;
#pragma unroll
    for (int q = 0; q < 4; ++q) {
      v[q] -= mean;
      ss += v[q][0] * v[q][0] + v[q][1] * v[q][1]
          + v[q][2] * v[q][2] + v[q][3] * v[q][3];
    }
    ss += __shfl_xor(ss, 1); ss += __shfl_xor(ss, 2);
    ss += __shfl_xor(ss, 4); ss += __shfl_xor(ss, 8);
    float rs = rsqrtf(ss * (1.f / 256.f) + 1e-5f);
#pragma unroll
    for (int q = 0; q < 4; ++q) {
      f32x4 y = v[q] * rs * sca[q] + lba[q];
      *(f32x4*)(xres + row * 256 + q * 64 + tx * 4) = y;
    }
  }
}

// ---------------- doc attention: block=(batch,head), 256 thr, 1 row/thread --
__global__ __launch_bounds__(256) void k_attn_doc(const float* __restrict__ qkv,
    float* __restrict__ o, int b0) {
  __shared__ f32x4 Ks[256 * 8];
  __shared__ f32x4 Vs[256 * 8];
  int bl = blockIdx.x >> 3, h = blockIdx.x & 7;
  int tid = threadIdx.x;
  const float* base = qkv + (size_t)bl * 256 * 768;
  int hc = h * 32;
  for (int idx = tid; idx < 2048; idx += 256) {
    int s = idx >> 3, w = idx & 7;
    Ks[idx] = *(const f32x4*)(base + (size_t)s * 768 + 256 + hc + w * 4);
    Vs[idx] = *(const f32x4*)(base + (size_t)s * 768 + 512 + hc + w * 4);
  }
  __syncthreads();
  f32x4 q[8], acc[8];
  const float* qp = base + (size_t)tid * 768 + hc;
#pragma unroll
  for (int w = 0; w < 8; ++w) { q[w] = *(const f32x4*)(qp + 4 * w); acc[w] = 0.f; }
  float m = -1e30f, l = 0.f;
  const float scale = 0.17677669529663687f;
  for (int j = 0; j < 256; ++j) {
    const f32x4* kr = &Ks[j * 8];
    f32x4 da = q[0] * kr[0];         // two independent partial chains
    f32x4 db = q[1] * kr[1];
#pragma unroll
    for (int w = 2; w < 8; w += 2) {
      da += q[w] * kr[w];
      db += q[w + 1] * kr[w + 1];
    }
    f32x4 d4 = da + db;
    float s_ = (d4[0] + d4[1] + d4[2] + d4[3]) * scale;
    float mn = fmaxf(m, s_);
    float p = __expf(s_ - mn);
    if (mn > m) {
      float al = __expf(m - mn);
      l *= al;
#pragma unroll
      for (int w = 0; w < 8; ++w) acc[w] *= al;
      m = mn;
    }
    l += p;
    const f32x4* vr = &Vs[j * 8];
#pragma unroll
    for (int w = 0; w < 8; ++w) acc[w] += p * vr[w];
  }
  float inv = 1.f / l;
  float* op = o + ((size_t)(b0 + bl) * 256 + tid) * DMODEL + hc;
#pragma unroll
  for (int w = 0; w < 8; ++w) *(f32x4*)(op + 4 * w) = acc[w] * inv;
}

// ---------------- query attention: block=batch, 256 thr=(head,row) ----------
__global__ __launch_bounds__(256) void k_attn_qry(const float* __restrict__ qkv,
    float* __restrict__ o) {
  __shared__ f32x4 Ks[32 * 64];  // [s][c], c = full 256-float row / 4
  __shared__ f32x4 Vs[32 * 64];
  int bl = blockIdx.x;
  int tid = threadIdx.x;
  const float* base = qkv + (size_t)bl * 32 * 768;
  for (int idx = tid; idx < 2048; idx += 256) {
    int s = idx >> 6, c = idx & 63;
    Ks[idx] = *(const f32x4*)(base + (size_t)s * 768 + 256 + c * 4);
    Vs[idx] = *(const f32x4*)(base + (size_t)s * 768 + 512 + c * 4);
  }
  __syncthreads();
  int h = tid >> 5, row = tid & 31;
  int hc = h * 32;
  f32x4 q[8], acc[8];
  const float* qp = base + (size_t)row * 768 + hc;
#pragma unroll
  for (int w = 0; w < 8; ++w) { q[w] = *(const f32x4*)(qp + 4 * w); acc[w] = 0.f; }
  float m = -1e30f, l = 0.f;
  const float scale = 0.17677669529663687f;
  for (int j = 0; j < 32; ++j) {
    const f32x4* kr = &Ks[j * 64 + h * 8];
    f32x4 da = q[0] * kr[0];
    f32x4 db = q[1] * kr[1];
#pragma unroll
    for (int w = 2; w < 8; w += 2) {
      da += q[w] * kr[w];
      db += q[w + 1] * kr[w + 1];
    }
    f32x4 d4 = da + db;
    float s_ = (d4[0] + d4[1] + d4[2] + d4[3]) * scale;
    float mn = fmaxf(m, s_);
    float p = __expf(s_ - mn);
    if (mn > m) {
      float al = __expf(m - mn);
      l *= al;
#pragma unroll
      for (int w = 0; w < 8; ++w) acc[w] *= al;
      m = mn;
    }
    l += p;
    const f32x4* vr = &Vs[j * 64 + h * 8];
#pragma unroll
    for (int w = 0; w < 8; ++w) acc[w] += p * vr[w];
  }
  float inv = 1.f / l;
  float* op = o + ((size_t)bl * 32 + row) * DMODEL + hc;
#pragma unroll
  for (int w = 0; w < 8; ++w) *(f32x4*)(op + 4 * w) = acc[w] * inv;
}

// ---------------- fused scoring (R5 verbatim) ----------------
__global__ __launch_bounds__(256) void k_score(
    const int* __restrict__ qids, const int* __restrict__ dids,
    const float* __restrict__ emb, const float* __restrict__ xq,
    const float* __restrict__ xd, const float* __restrict__ a_ptr,
    const float* __restrict__ mlp_w, float* __restrict__ out) {
  __shared__ float qmix[32 * 256];
  __shared__ float qks[32 * 11];
  __shared__ float qmask_s[32];
  int b = blockIdx.x, tid = threadIdx.x;
  float av = a_ptr[0], aw = 1.f - av;
  for (int q = 0; q < 32; ++q) {
    int qid = qids[b * 32 + q];
    float qm = qid > 0 ? 1.f : 0.f;
    float ev = emb[(size_t)qid * 256 + tid];
    float xv = xq[((size_t)b * 32 + q) * 256 + tid];
    qmix[q * 256 + tid] = (av * ev + aw * xv) * qm;
    if (tid == 0) qmask_s[q] = qm;
  }
  for (int i = tid; i < 352; i += 256) qks[i] = 0.f;
  __syncthreads();
  int j = tid;
  int did = dids[b * 256 + j];
  float dmask = did > 0 ? 1.f : 0.f;
  float sim[32];
#pragma unroll
  for (int q = 0; q < 32; ++q) sim[q] = 0.f;
  const float4* de = (const float4*)(emb + (size_t)did * 256);
  const float4* dxp = (const float4*)(xd + ((size_t)b * 256 + j) * 256);
  for (int c = 0; c < 4; ++c) {
    float4 dreg[16];
#pragma unroll
    for (int w = 0; w < 16; ++w) {
      float4 e = de[c * 16 + w], x = dxp[c * 16 + w];
      dreg[w].x = av * e.x + aw * x.x;
      dreg[w].y = av * e.y + aw * x.y;
      dreg[w].z = av * e.z + aw * x.z;
      dreg[w].w = av * e.w + aw * x.w;
    }
#pragma unroll
    for (int q = 0; q < 32; ++q) {
      const float4* qp = (const float4*)&qmix[q * 256 + c * 64];
      float d_ = 0.f;
#pragma unroll
      for (int w = 0; w < 16; ++w) {
        float4 t = qp[w];
        d_ += t.x * dreg[w].x + t.y * dreg[w].y + t.z * dreg[w].z + t.w * dreg[w].w;
      }
      sim[q] += d_;
    }
  }
  const float MU[11] = {1.f, 0.9f, 0.7f, 0.5f, 0.3f, 0.1f, -0.1f, -0.3f, -0.5f, -0.7f, -0.9f};
  const float IC[11] = {5e7f, 50.f, 50.f, 50.f, 50.f, 50.f, 50.f, 50.f, 50.f, 50.f, 50.f};
  for (int q = 0; q < 32; ++q) {
    float s = sim[q];
    float f = dmask * qmask_s[q];
#pragma unroll
    for (int k = 0; k < 11; ++k) {
      float d_ = s - MU[k];
      float v = expf(-d_ * d_ * IC[k]) * f;
#pragma unroll
      for (int o = 32; o > 0; o >>= 1) v += __shfl_xor(v, o);
      if ((tid & 63) == 0) atomicAdd(&qks[q * 11 + k], v);
    }
  }
  __syncthreads();
  if (tid < 32) {
    float qm = qmask_s[tid];
    float p = 0.f;
#pragma unroll
    for (int k = 0; k < 11; ++k) {
      float qv = qks[tid * 11 + k];
      p += mlp_w[k] * (qm * logf(fmaxf(qv, 1e-10f)) + qv * (1.f / 256.f));
    }
#pragma unroll
    for (int o = 16; o > 0; o >>= 1) p += __shfl_xor(p, o);
    if (tid == 0) out[b] = p;
  }
}

extern "C" void kernel_launch(void* const* d_in, const int* in_sizes, int n_in,
                              void* d_out, int out_size, void* d_ws, size_t ws_size,
                              hipStream_t stream) {
  const int* qids = (const int*)d_in[0];
  const int* dids = (const int*)d_in[1];
  const float* emb = (const float*)d_in[2];
  const float* a = (const float*)d_in[3];
  const float* mlp_w = (const float*)d_in[4];
  const float* Wqkv = (const float*)d_in[5];
  const float* bqkv = (const float*)d_in[6];
  const float* Wo = (const float*)d_in[7];
  const float* bo = (const float*)d_in[8];
  const float* l1s = (const float*)d_in[9];
  const float* l1b = (const float*)d_in[10];
  const float* W1 = (const float*)d_in[11];
  const float* b1 = (const float*)d_in[12];
  const float* W2 = (const float*)d_in[13];
  const float* b2 = (const float*)d_in[14];
  const float* l2s = (const float*)d_in[15];
  const float* l2b = (const float*)d_in[16];
  float* out = (float*)d_out;
  float* ws = (float*)d_ws;

  const int TOK = 73728;                    // 65536 doc + 8192 query tokens
  const size_t QRY_QKV = (size_t)8192 * 768;  // 6,291,456 floats

  size_t wsf = ws_size / 4;
  const size_t fixed = 2 * (size_t)TOK * 256 + 65536;
  const int cbs[] = {256, 128, 64, 32, 16, 8};
  const int fcs[] = {24576, 12288, 9216, 6144, 3072, 2048};
  int CB = 8, FC = 2048;
  for (int i = 0; i < 6; ++i) {
    size_t sc = (size_t)cbs[i] * 196608;
    size_t s2 = (size_t)fcs[i] * 2048;
    size_t scr = sc > s2 ? sc : s2;
    if (scr < QRY_QKV) scr = QRY_QKV;
    if (fixed + scr <= wsf) { CB = cbs[i]; FC = fcs[i]; break; }
  }

  float* x       = ws;
  float* t0      = x + (size_t)TOK * 256;
  float* pe      = t0 + (size_t)TOK * 256;
  float* scratch = pe + 65536;

  k_pe<<<256, 256, 0, stream>>>(pe);
  k_embed<<<TOK / 4, 256, 0, stream>>>(dids, qids, emb, pe, x);

  for (int l = 0; l < 2; ++l) {
    const float* wq = Wqkv + (size_t)l * 768 * 256;
    const float* bq = bqkv + l * 768;
    const float* wo = Wo + (size_t)l * 256 * 256;
    const float* bo_ = bo + l * 256;
    const float* w1 = W1 + (size_t)l * 2048 * 256;
    const float* b1_ = b1 + l * 2048;
    const float* w2 = W2 + (size_t)l * 256 * 2048;
    const float* b2_ = b2 + l * 256;

    // doc QKV + attention, chunked by CB batches (CB*256 tokens)
    for (int c = 0; c < 256; c += CB) {
      int Mc = CB * 256;
      k_gemm<false><<<dim3(6, Mc / 128), 256, 0, stream>>>(
          x + (size_t)c * 65536, wq, bq, scratch, Mc, 768, 256);
      k_attn_doc<<<CB * 8, 256, 0, stream>>>(scratch, t0, c);
    }
    // query QKV + attention (single chunk: 8192 tokens)
    k_gemm<false><<<dim3(6, 64), 256, 0, stream>>>(
        x + (size_t)65536 * 256, wq, bq, scratch, 8192, 768, 256);
    k_attn_qry<<<256, 256, 0, stream>>>(scratch, t0 + (size_t)65536 * 256);
    // Wo + bias + residual + LN1 over all tokens, in-place into x
    k_gemm_ln<<<TOK / 64, 256, 0, stream>>>(t0, wo, bo_, x,
        l1s + l * 256, l1b + l * 256, TOK, 256);
    // FFN in chunks of FC tokens
    for (int f = 0; f < TOK; f += FC) {
      k_gemm<true><<<dim3(16, FC / 128), 256, 0, stream>>>(
          x + (size_t)f * 256, w1, b1_, scratch, FC, 2048, 256);
      k_gemm_ln<<<FC / 64, 256, 0, stream>>>(scratch, w2, b2_, x + (size_t)f * 256,
          l2s + l * 256, l2b + l * 256, FC, 2048);
    }
  }

  k_score<<<256, 256, 0, stream>>>(qids, dids, emb, x + (size_t)65536 * 256,
                                   x, a, mlp_w, out);
}

// Round 11
// 6548.262 us; speedup vs baseline: 2.8353x; 1.0452x over previous
//
#include <hip/hip_runtime.h>
#include <math.h>

// KNRM-style ranker, fp32 end-to-end.
// R11 vs R10 (6.84ms): FFN re-split over the ff dimension (4 slices of 512)
// instead of token chunks. R10's W2-LN ran at 51 TF because FC=12288 token
// chunks gave a 192-block grid (1 block/CU, 1 wave/SIMD). Now:
//   W1-slice: k_gemm M=73728 N=512 K=256 (grid 2304) -> h_part (37.75M fl)
//   W2-slice: k_gemm M=73728 N=256 K=512 ldw=2048, ACC into t0 (grid 1152)
//   LN: proven R3 k_addln (t0 includes b2 from slice 0).
// ws layout 302MB < proven 327MB floor. Wo keeps fused k_gemm_ln (grid 1152).
// k_gemm: +ldw param, +template<bool ACC> epilogue. Attn/score unchanged.

#define DMODEL 256
typedef float f32x4 __attribute__((ext_vector_type(4)));

// ---------------- positional-encoding table: pe[s][d], s<256 ----------------
__global__ __launch_bounds__(256) void k_pe(float* __restrict__ pe) {
  int s = blockIdx.x, d = threadIdx.x;
  int i2 = d & ~1;
  float freq = expf((float)i2 * (-9.210340371976184f / 256.f));
  float ang = (float)s * freq;
  pe[s * 256 + d] = (d & 1) ? cosf(ang) : sinf(ang);
}

// ---------------- embed (doc+query merged), 4 tokens / 256-thr block --------
__global__ __launch_bounds__(256) void k_embed(const int* __restrict__ dids,
    const int* __restrict__ qids, const float* __restrict__ emb,
    const float* __restrict__ pe, float* __restrict__ out_x) {
  int tid = threadIdx.x;
  int tok = blockIdx.x * 4 + (tid >> 6);
  int lane = tid & 63;
  int d0 = lane * 4;
  int id, s;
  if (tok < 65536) { id = dids[tok]; s = tok & 255; }
  else             { id = qids[tok - 65536]; s = (tok - 65536) & 31; }
  float m = id > 0 ? 2.f : 0.f;
  float4 e = *(const float4*)(emb + (size_t)id * DMODEL + d0);
  float4 p = *(const float4*)(pe + s * 256 + d0);
  float4 o;
  o.x = m * e.x + p.x; o.y = m * e.y + p.y;
  o.z = m * e.z + p.z; o.w = m * e.w + p.w;
  *(float4*)(out_x + (size_t)tok * DMODEL + d0) = o;
}

// ---------------- fp32 GEMM: out[M,N] = X[M,K] @ W[N,K(ldw)]^T (+bias|+=) ---
// 128x128x16 tile, 256 threads, ping-pong staging, wave-quadrant reads.
// ACC=false: out = acc + bias (opt ReLU). ACC=true: out += acc (bias unused).
template<bool RELU, bool ACC>
__global__ __launch_bounds__(256) void k_gemm(const float* __restrict__ X,
    const float* __restrict__ W, const float* __restrict__ bias,
    float* __restrict__ out, int M, int N, int K, int ldw) {
  __shared__ float As[2][16][128];
  __shared__ float Bs[2][16][128];
  int n0 = blockIdx.x * 128;
  int m0 = blockIdx.y * 128;
  int tid = threadIdx.x;
  const int wv = tid >> 6, lane = tid & 63;
  const int r8 = lane >> 3, c8 = lane & 7;
  const int R0 = (wv & 1) * 64 + r8 * 4;
  const int C0 = (wv >> 1) * 64 + c8 * 4;
  int lr = tid >> 1;
  int lk = (tid & 1) << 3;
  const float* Xp = X + (size_t)(m0 + lr) * K + lk;
  const float* Wp = W + (size_t)(n0 + lr) * ldw + lk;

  float acc[8][8];
#pragma unroll
  for (int i = 0; i < 8; ++i)
#pragma unroll
    for (int j = 0; j < 8; ++j) acc[i][j] = 0.f;

  float4 a0, a1, b0, b1;

#define GLOADT(KT) do { \
    a0 = *(const float4*)(Xp + (KT)); a1 = *(const float4*)(Xp + (KT) + 4); \
    b0 = *(const float4*)(Wp + (KT)); b1 = *(const float4*)(Wp + (KT) + 4); } while (0)

#define LWRITE(BUF) do { \
    As[BUF][lk + 0][lr] = a0.x; As[BUF][lk + 1][lr] = a0.y; \
    As[BUF][lk + 2][lr] = a0.z; As[BUF][lk + 3][lr] = a0.w; \
    As[BUF][lk + 4][lr] = a1.x; As[BUF][lk + 5][lr] = a1.y; \
    As[BUF][lk + 6][lr] = a1.z; As[BUF][lk + 7][lr] = a1.w; \
    Bs[BUF][lk + 0][lr] = b0.x; Bs[BUF][lk + 1][lr] = b0.y; \
    Bs[BUF][lk + 2][lr] = b0.z; Bs[BUF][lk + 3][lr] = b0.w; \
    Bs[BUF][lk + 4][lr] = b1.x; Bs[BUF][lk + 5][lr] = b1.y; \
    Bs[BUF][lk + 6][lr] = b1.z; Bs[BUF][lk + 7][lr] = b1.w; } while (0)

#define COMPT(BUF) do { \
    _Pragma("unroll") \
    for (int k = 0; k < 16; ++k) { \
      float av[8], bv[8]; \
      *(float4*)&av[0] = *(const float4*)&As[BUF][k][R0]; \
      *(float4*)&av[4] = *(const float4*)&As[BUF][k][R0 + 32]; \
      *(float4*)&bv[0] = *(const float4*)&Bs[BUF][k][C0]; \
      *(float4*)&bv[4] = *(const float4*)&Bs[BUF][k][C0 + 32]; \
      _Pragma("unroll") \
      for (int i = 0; i < 8; ++i) \
        _Pragma("unroll") \
        for (int j = 0; j < 8; ++j) \
          acc[i][j] += av[i] * bv[j]; \
    } } while (0)

  const int nt = K >> 4;  // 16/32/128: even
  GLOADT(0);
  LWRITE(0);
  __syncthreads();
  for (int t = 0; t < nt; t += 2) {
    int k1 = (t + 1) * 16;
    GLOADT(k1);
    COMPT(0);
    LWRITE(1);
    __syncthreads();
    if (t + 2 < nt) {
      int k2 = (t + 2) * 16;
      GLOADT(k2);
      COMPT(1);
      LWRITE(0);
    } else {
      COMPT(1);
    }
    __syncthreads();
  }
#undef GLOADT
#undef LWRITE
#undef COMPT

#pragma unroll
  for (int i = 0; i < 8; ++i) {
    int mr = m0 + (wv & 1) * 64 + ((i < 4) ? (r8 * 4 + i) : (32 + r8 * 4 + i - 4));
#pragma unroll
    for (int jb = 0; jb < 2; ++jb) {
      int nc = n0 + (wv >> 1) * 64 + jb * 32 + c8 * 4;
      float4 o4;
      if (ACC) {
        float4 pv = *(const float4*)(out + (size_t)mr * N + nc);
        o4.x = acc[i][jb * 4 + 0] + pv.x;
        o4.y = acc[i][jb * 4 + 1] + pv.y;
        o4.z = acc[i][jb * 4 + 2] + pv.z;
        o4.w = acc[i][jb * 4 + 3] + pv.w;
      } else {
        float4 bz = *(const float4*)(bias + nc);
        o4.x = acc[i][jb * 4 + 0] + bz.x;
        o4.y = acc[i][jb * 4 + 1] + bz.y;
        o4.z = acc[i][jb * 4 + 2] + bz.z;
        o4.w = acc[i][jb * 4 + 3] + bz.w;
      }
      if (RELU) {
        o4.x = fmaxf(o4.x, 0.f); o4.y = fmaxf(o4.y, 0.f);
        o4.z = fmaxf(o4.z, 0.f); o4.w = fmaxf(o4.w, 0.f);
      }
      *(float4*)(out + (size_t)mr * N + nc) = o4;
    }
  }
}

// ---------------- GEMM (N=256) fused bias+residual+LayerNorm (Wo only) ------
__global__ __launch_bounds__(256) void k_gemm_ln(const float* __restrict__ X,
    const float* __restrict__ W, const float* __restrict__ bias,
    float* __restrict__ xres, const float* __restrict__ lns,
    const float* __restrict__ lnb, int M, int K) {
  __shared__ float As[2][16][64];
  __shared__ float Bs[2][16][256];
  const int tid = threadIdx.x;
  const int m0 = blockIdx.x * 64;
  const int tx = tid & 15, ty = tid >> 4;
  const int rowA = tid & 63;
  const int kqA = (tid >> 6) << 2;
  const float* Xp = X + (size_t)(m0 + rowA) * K + kqA;
  const float* Wp = W + (size_t)tid * K;

  f32x4 acc[4][4];
#pragma unroll
  for (int r = 0; r < 4; ++r)
#pragma unroll
    for (int q = 0; q < 4; ++q) acc[r][q] = 0.f;

  f32x4 a, b0, b1, b2, b3;

#define GL(KT) do { \
    a  = *(const f32x4*)(Xp + (KT)); \
    b0 = *(const f32x4*)(Wp + (KT));      b1 = *(const f32x4*)(Wp + (KT) + 4); \
    b2 = *(const f32x4*)(Wp + (KT) + 8);  b3 = *(const f32x4*)(Wp + (KT) + 12); } while (0)

#define LW(BUF) do { \
    As[BUF][kqA + 0][rowA] = a[0]; As[BUF][kqA + 1][rowA] = a[1]; \
    As[BUF][kqA + 2][rowA] = a[2]; As[BUF][kqA + 3][rowA] = a[3]; \
    Bs[BUF][ 0][tid] = b0[0]; Bs[BUF][ 1][tid] = b0[1]; \
    Bs[BUF][ 2][tid] = b0[2]; Bs[BUF][ 3][tid] = b0[3]; \
    Bs[BUF][ 4][tid] = b1[0]; Bs[BUF][ 5][tid] = b1[1]; \
    Bs[BUF][ 6][tid] = b1[2]; Bs[BUF][ 7][tid] = b1[3]; \
    Bs[BUF][ 8][tid] = b2[0]; Bs[BUF][ 9][tid] = b2[1]; \
    Bs[BUF][10][tid] = b2[2]; Bs[BUF][11][tid] = b2[3]; \
    Bs[BUF][12][tid] = b3[0]; Bs[BUF][13][tid] = b3[1]; \
    Bs[BUF][14][tid] = b3[2]; Bs[BUF][15][tid] = b3[3]; } while (0)

#define CP(BUF) do { \
    _Pragma("unroll") \
    for (int k = 0; k < 16; ++k) { \
      f32x4 av = *(const f32x4*)&As[BUF][k][ty * 4]; \
      f32x4 bv0 = *(const f32x4*)&Bs[BUF][k][tx * 4]; \
      f32x4 bv1 = *(const f32x4*)&Bs[BUF][k][64 + tx * 4]; \
      f32x4 bv2 = *(const f32x4*)&Bs[BUF][k][128 + tx * 4]; \
      f32x4 bv3 = *(const f32x4*)&Bs[BUF][k][192 + tx * 4]; \
      _Pragma("unroll") \
      for (int r = 0; r < 4; ++r) { \
        acc[r][0] += av[r] * bv0; acc[r][1] += av[r] * bv1; \
        acc[r][2] += av[r] * bv2; acc[r][3] += av[r] * bv3; \
      } \
    } } while (0)

  const int nt = K >> 4;
  GL(0);
  LW(0);
  __syncthreads();
  for (int t = 0; t < nt; t += 2) {
    GL((t + 1) * 16);
    CP(0);
    LW(1);
    __syncthreads();
    if (t + 2 < nt) {
      GL((t + 2) * 16);
      CP(1);
      LW(0);
    } else {
      CP(1);
    }
    __syncthreads();
  }
#undef GL
#undef LW
#undef CP

  f32x4 bza[4], sca[4], lba[4];
#pragma unroll
  for (int q = 0; q < 4; ++q) {
    int c = q * 64 + tx * 4;
    bza[q] = *(const f32x4*)(bias + c);
    sca[q] = *(const f32x4*)(lns + c);
    lba[q] = *(const f32x4*)(lnb + c);
  }
#pragma unroll
  for (int r = 0; r < 4; ++r) {
    size_t row = (size_t)m0 + ty * 4 + r;
    f32x4 v[4];
    float ps = 0.f;
#pragma unroll
    for (int q = 0; q < 4; ++q) {
      f32x4 xr = *(const f32x4*)(xres + row * 256 + q * 64 + tx * 4);
      v[q] = acc[r][q] + bza[q] + xr;
      ps += v[q][0] + v[q][1] + v[q][2] + v[q][3];
    }
    ps += __shfl_xor(ps, 1); ps += __shfl_xor(ps, 2);
    ps += __shfl_xor(ps, 4); ps += __shfl_xor(ps, 8);
    float mean = ps * (1.f / 256.f);
    float ss = 0.f;
#pragma unroll
    for (int q = 0; q < 4; ++q) {
      v[q] -= mean;
      ss += v[q][0] * v[q][0] + v[q][1] * v[q][1]
          + v[q][2] * v[q][2] + v[q][3] * v[q][3];
    }
    ss += __shfl_xor(ss, 1); ss += __shfl_xor(ss, 2);
    ss += __shfl_xor(ss, 4); ss += __shfl_xor(ss, 8);
    float rs = rsqrtf(ss * (1.f / 256.f) + 1e-5f);
#pragma unroll
    for (int q = 0; q < 4; ++q) {
      f32x4 y = v[q] * rs * sca[q] + lba[q];
      *(f32x4*)(xres + row * 256 + q * 64 + tx * 4) = y;
    }
  }
}

// ---------------- residual add + LayerNorm (R3-proven, 4 tokens/block) ------
__global__ __launch_bounds__(256) void k_addln(float* __restrict__ x,
    const float* __restrict__ t, const float* __restrict__ sc,
    const float* __restrict__ bi) {
  int tid = threadIdx.x;
  size_t tok = (size_t)blockIdx.x * 4 + (tid >> 6);
  int lane = tid & 63;
  float4 xv = *(const float4*)(x + tok * 256 + lane * 4);
  float4 tv = *(const float4*)(t + tok * 256 + lane * 4);
  float4 v;
  v.x = xv.x + tv.x; v.y = xv.y + tv.y; v.z = xv.z + tv.z; v.w = xv.w + tv.w;
  float s1 = v.x + v.y + v.z + v.w;
#pragma unroll
  for (int o = 32; o > 0; o >>= 1) s1 += __shfl_xor(s1, o);
  float mean = s1 * (1.f / 256.f);
  float dx = v.x - mean, dy = v.y - mean, dz = v.z - mean, dw = v.w - mean;
  float s2 = dx * dx + dy * dy + dz * dz + dw * dw;
#pragma unroll
  for (int o = 32; o > 0; o >>= 1) s2 += __shfl_xor(s2, o);
  float rs = rsqrtf(s2 * (1.f / 256.f) + 1e-5f);
  float4 s4 = *(const float4*)(sc + lane * 4);
  float4 b4 = *(const float4*)(bi + lane * 4);
  float4 ov;
  ov.x = dx * rs * s4.x + b4.x;
  ov.y = dy * rs * s4.y + b4.y;
  ov.z = dz * rs * s4.z + b4.z;
  ov.w = dw * rs * s4.w + b4.w;
  *(float4*)(x + tok * 256 + lane * 4) = ov;
}

// ---------------- doc attention: block=(batch,head), 256 thr, 1 row/thread --
__global__ __launch_bounds__(256) void k_attn_doc(const float* __restrict__ qkv,
    float* __restrict__ o, int b0) {
  __shared__ f32x4 Ks[256 * 8];
  __shared__ f32x4 Vs[256 * 8];
  int bl = blockIdx.x >> 3, h = blockIdx.x & 7;
  int tid = threadIdx.x;
  const float* base = qkv + (size_t)bl * 256 * 768;
  int hc = h * 32;
  for (int idx = tid; idx < 2048; idx += 256) {
    int s = idx >> 3, w = idx & 7;
    Ks[idx] = *(const f32x4*)(base + (size_t)s * 768 + 256 + hc + w * 4);
    Vs[idx] = *(const f32x4*)(base + (size_t)s * 768 + 512 + hc + w * 4);
  }
  __syncthreads();
  f32x4 q[8], acc[8];
  const float* qp = base + (size_t)tid * 768 + hc;
#pragma unroll
  for (int w = 0; w < 8; ++w) { q[w] = *(const f32x4*)(qp + 4 * w); acc[w] = 0.f; }
  float m = -1e30f, l = 0.f;
  const float scale = 0.17677669529663687f;
  for (int j = 0; j < 256; ++j) {
    const f32x4* kr = &Ks[j * 8];
    f32x4 da = q[0] * kr[0];
    f32x4 db = q[1] * kr[1];
#pragma unroll
    for (int w = 2; w < 8; w += 2) {
      da += q[w] * kr[w];
      db += q[w + 1] * kr[w + 1];
    }
    f32x4 d4 = da + db;
    float s_ = (d4[0] + d4[1] + d4[2] + d4[3]) * scale;
    float mn = fmaxf(m, s_);
    float p = __expf(s_ - mn);
    if (mn > m) {
      float al = __expf(m - mn);
      l *= al;
#pragma unroll
      for (int w = 0; w < 8; ++w) acc[w] *= al;
      m = mn;
    }
    l += p;
    const f32x4* vr = &Vs[j * 8];
#pragma unroll
    for (int w = 0; w < 8; ++w) acc[w] += p * vr[w];
  }
  float inv = 1.f / l;
  float* op = o + ((size_t)(b0 + bl) * 256 + tid) * DMODEL + hc;
#pragma unroll
  for (int w = 0; w < 8; ++w) *(f32x4*)(op + 4 * w) = acc[w] * inv;
}

// ---------------- query attention: block=batch, 256 thr=(head,row) ----------
__global__ __launch_bounds__(256) void k_attn_qry(const float* __restrict__ qkv,
    float* __restrict__ o) {
  __shared__ f32x4 Ks[32 * 64];
  __shared__ f32x4 Vs[32 * 64];
  int bl = blockIdx.x;
  int tid = threadIdx.x;
  const float* base = qkv + (size_t)bl * 32 * 768;
  for (int idx = tid; idx < 2048; idx += 256) {
    int s = idx >> 6, c = idx & 63;
    Ks[idx] = *(const f32x4*)(base + (size_t)s * 768 + 256 + c * 4);
    Vs[idx] = *(const f32x4*)(base + (size_t)s * 768 + 512 + c * 4);
  }
  __syncthreads();
  int h = tid >> 5, row = tid & 31;
  int hc = h * 32;
  f32x4 q[8], acc[8];
  const float* qp = base + (size_t)row * 768 + hc;
#pragma unroll
  for (int w = 0; w < 8; ++w) { q[w] = *(const f32x4*)(qp + 4 * w); acc[w] = 0.f; }
  float m = -1e30f, l = 0.f;
  const float scale = 0.17677669529663687f;
  for (int j = 0; j < 32; ++j) {
    const f32x4* kr = &Ks[j * 64 + h * 8];
    f32x4 da = q[0] * kr[0];
    f32x4 db = q[1] * kr[1];
#pragma unroll
    for (int w = 2; w < 8; w += 2) {
      da += q[w] * kr[w];
      db += q[w + 1] * kr[w + 1];
    }
    f32x4 d4 = da + db;
    float s_ = (d4[0] + d4[1] + d4[2] + d4[3]) * scale;
    float mn = fmaxf(m, s_);
    float p = __expf(s_ - mn);
    if (mn > m) {
      float al = __expf(m - mn);
      l *= al;
#pragma unroll
      for (int w = 0; w < 8; ++w) acc[w] *= al;
      m = mn;
    }
    l += p;
    const f32x4* vr = &Vs[j * 64 + h * 8];
#pragma unroll
    for (int w = 0; w < 8; ++w) acc[w] += p * vr[w];
  }
  float inv = 1.f / l;
  float* op = o + ((size_t)bl * 32 + row) * DMODEL + hc;
#pragma unroll
  for (int w = 0; w < 8; ++w) *(f32x4*)(op + 4 * w) = acc[w] * inv;
}

// ---------------- fused scoring (R5 verbatim) ----------------
__global__ __launch_bounds__(256) void k_score(
    const int* __restrict__ qids, const int* __restrict__ dids,
    const float* __restrict__ emb, const float* __restrict__ xq,
    const float* __restrict__ xd, const float* __restrict__ a_ptr,
    const float* __restrict__ mlp_w, float* __restrict__ out) {
  __shared__ float qmix[32 * 256];
  __shared__ float qks[32 * 11];
  __shared__ float qmask_s[32];
  int b = blockIdx.x, tid = threadIdx.x;
  float av = a_ptr[0], aw = 1.f - av;
  for (int q = 0; q < 32; ++q) {
    int qid = qids[b * 32 + q];
    float qm = qid > 0 ? 1.f : 0.f;
    float ev = emb[(size_t)qid * 256 + tid];
    float xv = xq[((size_t)b * 32 + q) * 256 + tid];
    qmix[q * 256 + tid] = (av * ev + aw * xv) * qm;
    if (tid == 0) qmask_s[q] = qm;
  }
  for (int i = tid; i < 352; i += 256) qks[i] = 0.f;
  __syncthreads();
  int j = tid;
  int did = dids[b * 256 + j];
  float dmask = did > 0 ? 1.f : 0.f;
  float sim[32];
#pragma unroll
  for (int q = 0; q < 32; ++q) sim[q] = 0.f;
  const float4* de = (const float4*)(emb + (size_t)did * 256);
  const float4* dxp = (const float4*)(xd + ((size_t)b * 256 + j) * 256);
  for (int c = 0; c < 4; ++c) {
    float4 dreg[16];
#pragma unroll
    for (int w = 0; w < 16; ++w) {
      float4 e = de[c * 16 + w], x = dxp[c * 16 + w];
      dreg[w].x = av * e.x + aw * x.x;
      dreg[w].y = av * e.y + aw * x.y;
      dreg[w].z = av * e.z + aw * x.z;
      dreg[w].w = av * e.w + aw * x.w;
    }
#pragma unroll
    for (int q = 0; q < 32; ++q) {
      const float4* qp = (const float4*)&qmix[q * 256 + c * 64];
      float d_ = 0.f;
#pragma unroll
      for (int w = 0; w < 16; ++w) {
        float4 t = qp[w];
        d_ += t.x * dreg[w].x + t.y * dreg[w].y + t.z * dreg[w].z + t.w * dreg[w].w;
      }
      sim[q] += d_;
    }
  }
  const float MU[11] = {1.f, 0.9f, 0.7f, 0.5f, 0.3f, 0.1f, -0.1f, -0.3f, -0.5f, -0.7f, -0.9f};
  const float IC[11] = {5e7f, 50.f, 50.f, 50.f, 50.f, 50.f, 50.f, 50.f, 50.f, 50.f, 50.f};
  for (int q = 0; q < 32; ++q) {
    float s = sim[q];
    float f = dmask * qmask_s[q];
#pragma unroll
    for (int k = 0; k < 11; ++k) {
      float d_ = s - MU[k];
      float v = expf(-d_ * d_ * IC[k]) * f;
#pragma unroll
      for (int o = 32; o > 0; o >>= 1) v += __shfl_xor(v, o);
      if ((tid & 63) == 0) atomicAdd(&qks[q * 11 + k], v);
    }
  }
  __syncthreads();
  if (tid < 32) {
    float qm = qmask_s[tid];
    float p = 0.f;
#pragma unroll
    for (int k = 0; k < 11; ++k) {
      float qv = qks[tid * 11 + k];
      p += mlp_w[k] * (qm * logf(fmaxf(qv, 1e-10f)) + qv * (1.f / 256.f));
    }
#pragma unroll
    for (int o = 16; o > 0; o >>= 1) p += __shfl_xor(p, o);
    if (tid == 0) out[b] = p;
  }
}

extern "C" void kernel_launch(void* const* d_in, const int* in_sizes, int n_in,
                              void* d_out, int out_size, void* d_ws, size_t ws_size,
                              hipStream_t stream) {
  const int* qids = (const int*)d_in[0];
  const int* dids = (const int*)d_in[1];
  const float* emb = (const float*)d_in[2];
  const float* a = (const float*)d_in[3];
  const float* mlp_w = (const float*)d_in[4];
  const float* Wqkv = (const float*)d_in[5];
  const float* bqkv = (const float*)d_in[6];
  const float* Wo = (const float*)d_in[7];
  const float* bo = (const float*)d_in[8];
  const float* l1s = (const float*)d_in[9];
  const float* l1b = (const float*)d_in[10];
  const float* W1 = (const float*)d_in[11];
  const float* b1 = (const float*)d_in[12];
  const float* W2 = (const float*)d_in[13];
  const float* b2 = (const float*)d_in[14];
  const float* l2s = (const float*)d_in[15];
  const float* l2b = (const float*)d_in[16];
  float* out = (float*)d_out;
  float* ws = (float*)d_ws;

  const int TOK = 73728;                      // 65536 doc + 8192 query tokens
  const size_t QRY_QKV = (size_t)8192 * 768;  // 6.29M floats

  size_t wsf = ws_size / 4;
  const size_t fixed = 2 * (size_t)TOK * 256 + 65536;  // x + t0 + pe
  // (FW, CB): ff-slice width, doc batches per QKV chunk.
  // scratch = max(TOK*FW (h_part), CB*196608 (qkv chunk), QRY_QKV)
  const int fws[] = {512, 256, 128};
  const int cbs[] = {128, 64, 32};
  int FW = 128, CB = 32;
  for (int i = 0; i < 3; ++i) {
    size_t scr = (size_t)TOK * fws[i];
    size_t sc2 = (size_t)cbs[i] * 196608;
    if (sc2 > scr) scr = sc2;
    if (QRY_QKV > scr) scr = QRY_QKV;
    if (fixed + scr <= wsf) { FW = fws[i]; CB = cbs[i]; break; }
  }
  size_t scrN = (size_t)TOK * FW;
  { size_t sc2 = (size_t)CB * 196608; if (sc2 > scrN) scrN = sc2;
    if (QRY_QKV > scrN) scrN = QRY_QKV; }

  float* x       = ws;
  float* t0      = x + (size_t)TOK * 256;
  float* pe      = t0 + (size_t)TOK * 256;
  float* scratch = pe + 65536;   // qkv chunk | h_part (never live together)

  k_pe<<<256, 256, 0, stream>>>(pe);
  k_embed<<<TOK / 4, 256, 0, stream>>>(dids, qids, emb, pe, x);

  for (int l = 0; l < 2; ++l) {
    const float* wq = Wqkv + (size_t)l * 768 * 256;
    const float* bq = bqkv + l * 768;
    const float* wo = Wo + (size_t)l * 256 * 256;
    const float* bo_ = bo + l * 256;
    const float* w1 = W1 + (size_t)l * 2048 * 256;
    const float* b1_ = b1 + l * 2048;
    const float* w2 = W2 + (size_t)l * 256 * 2048;
    const float* b2_ = b2 + l * 256;

    // doc QKV + attention, chunked by CB batches
    for (int c = 0; c < 256; c += CB) {
      int Mc = CB * 256;
      k_gemm<false, false><<<dim3(6, Mc / 128), 256, 0, stream>>>(
          x + (size_t)c * 65536, wq, bq, scratch, Mc, 768, 256, 256);
      k_attn_doc<<<CB * 8, 256, 0, stream>>>(scratch, t0, c);
    }
    // query QKV + attention
    k_gemm<false, false><<<dim3(6, 64), 256, 0, stream>>>(
        x + (size_t)65536 * 256, wq, bq, scratch, 8192, 768, 256, 256);
    k_attn_qry<<<256, 256, 0, stream>>>(scratch, t0 + (size_t)65536 * 256);
    // Wo + bias + residual + LN1, in-place into x (grid 1152)
    k_gemm_ln<<<TOK / 64, 256, 0, stream>>>(t0, wo, bo_, x,
        l1s + l * 256, l1b + l * 256, TOK, 256);
    // FFN: ff-sliced. t0 accumulates h@W2^T (+b2 via slice 0), then LN.
    int nparts = 2048 / FW;
    for (int p = 0; p < nparts; ++p) {
      // h_part = relu(x @ W1_p^T + b1_p): M=TOK, N=FW, K=256
      k_gemm<true, false><<<dim3(FW / 128, TOK / 128), 256, 0, stream>>>(
          x, w1 + (size_t)p * FW * 256, b1_ + p * FW, scratch, TOK, FW, 256, 256);
      // t0 (+)= h_part @ W2[:, p*FW:(p+1)*FW]^T: M=TOK, N=256, K=FW, ldw=2048
      if (p == 0)
        k_gemm<false, false><<<dim3(2, TOK / 128), 256, 0, stream>>>(
            scratch, w2, b2_, t0, TOK, 256, FW, 2048);
      else
        k_gemm<false, true><<<dim3(2, TOK / 128), 256, 0, stream>>>(
            scratch, w2 + (size_t)p * FW, b2_, t0, TOK, 256, FW, 2048);
    }
    // x = LN(x + t0) * l2s + l2b
    k_addln<<<TOK / 4, 256, 0, stream>>>(x, t0, l2s + l * 256, l2b + l * 256);
  }

  k_score<<<256, 256, 0, stream>>>(qids, dids, emb, x + (size_t)65536 * 256,
                                   x, a, mlp_w, out);
}

// Round 12
// 6405.063 us; speedup vs baseline: 2.8987x; 1.0224x over previous
//
#include <hip/hip_runtime.h>
#include <math.h>

// KNRM-style ranker, fp32 end-to-end.
// R12 vs R11 (6.55ms):
//  - k_score split into 2 blocks/batch (16 queries each, grid 512 -> 2
//    blocks/CU vs 1), per-wave qks slots (no LDS atomics), deterministic
//    partial buffer + tiny combine kernel (R11: 197us, 1 block/CU, 2112
//    dependent shfls + 1408 LDS atomics per thread-block).
//  - last W2 ff-slice fused with residual+LN via k_gemm_ln<ACCT0,ldw>
//    (removes k_addln dispatch + one t0 round-trip per layer).
// ws ladder unchanged (proven: ws < 352.6MB, >= ~252MB rung passes).

#define DMODEL 256
typedef float f32x4 __attribute__((ext_vector_type(4)));

// ---------------- positional-encoding table: pe[s][d], s<256 ----------------
__global__ __launch_bounds__(256) void k_pe(float* __restrict__ pe) {
  int s = blockIdx.x, d = threadIdx.x;
  int i2 = d & ~1;
  float freq = expf((float)i2 * (-9.210340371976184f / 256.f));
  float ang = (float)s * freq;
  pe[s * 256 + d] = (d & 1) ? cosf(ang) : sinf(ang);
}

// ---------------- embed (doc+query merged), 4 tokens / 256-thr block --------
__global__ __launch_bounds__(256) void k_embed(const int* __restrict__ dids,
    const int* __restrict__ qids, const float* __restrict__ emb,
    const float* __restrict__ pe, float* __restrict__ out_x) {
  int tid = threadIdx.x;
  int tok = blockIdx.x * 4 + (tid >> 6);
  int lane = tid & 63;
  int d0 = lane * 4;
  int id, s;
  if (tok < 65536) { id = dids[tok]; s = tok & 255; }
  else             { id = qids[tok - 65536]; s = (tok - 65536) & 31; }
  float m = id > 0 ? 2.f : 0.f;
  float4 e = *(const float4*)(emb + (size_t)id * DMODEL + d0);
  float4 p = *(const float4*)(pe + s * 256 + d0);
  float4 o;
  o.x = m * e.x + p.x; o.y = m * e.y + p.y;
  o.z = m * e.z + p.z; o.w = m * e.w + p.w;
  *(float4*)(out_x + (size_t)tok * DMODEL + d0) = o;
}

// ---------------- fp32 GEMM: out[M,N] = X[M,K] @ W[N,K(ldw)]^T (+bias|+=) ---
template<bool RELU, bool ACC>
__global__ __launch_bounds__(256) void k_gemm(const float* __restrict__ X,
    const float* __restrict__ W, const float* __restrict__ bias,
    float* __restrict__ out, int M, int N, int K, int ldw) {
  __shared__ float As[2][16][128];
  __shared__ float Bs[2][16][128];
  int n0 = blockIdx.x * 128;
  int m0 = blockIdx.y * 128;
  int tid = threadIdx.x;
  const int wv = tid >> 6, lane = tid & 63;
  const int r8 = lane >> 3, c8 = lane & 7;
  const int R0 = (wv & 1) * 64 + r8 * 4;
  const int C0 = (wv >> 1) * 64 + c8 * 4;
  int lr = tid >> 1;
  int lk = (tid & 1) << 3;
  const float* Xp = X + (size_t)(m0 + lr) * K + lk;
  const float* Wp = W + (size_t)(n0 + lr) * ldw + lk;

  float acc[8][8];
#pragma unroll
  for (int i = 0; i < 8; ++i)
#pragma unroll
    for (int j = 0; j < 8; ++j) acc[i][j] = 0.f;

  float4 a0, a1, b0, b1;

#define GLOADT(KT) do { \
    a0 = *(const float4*)(Xp + (KT)); a1 = *(const float4*)(Xp + (KT) + 4); \
    b0 = *(const float4*)(Wp + (KT)); b1 = *(const float4*)(Wp + (KT) + 4); } while (0)

#define LWRITE(BUF) do { \
    As[BUF][lk + 0][lr] = a0.x; As[BUF][lk + 1][lr] = a0.y; \
    As[BUF][lk + 2][lr] = a0.z; As[BUF][lk + 3][lr] = a0.w; \
    As[BUF][lk + 4][lr] = a1.x; As[BUF][lk + 5][lr] = a1.y; \
    As[BUF][lk + 6][lr] = a1.z; As[BUF][lk + 7][lr] = a1.w; \
    Bs[BUF][lk + 0][lr] = b0.x; Bs[BUF][lk + 1][lr] = b0.y; \
    Bs[BUF][lk + 2][lr] = b0.z; Bs[BUF][lk + 3][lr] = b0.w; \
    Bs[BUF][lk + 4][lr] = b1.x; Bs[BUF][lk + 5][lr] = b1.y; \
    Bs[BUF][lk + 6][lr] = b1.z; Bs[BUF][lk + 7][lr] = b1.w; } while (0)

#define COMPT(BUF) do { \
    _Pragma("unroll") \
    for (int k = 0; k < 16; ++k) { \
      float av[8], bv[8]; \
      *(float4*)&av[0] = *(const float4*)&As[BUF][k][R0]; \
      *(float4*)&av[4] = *(const float4*)&As[BUF][k][R0 + 32]; \
      *(float4*)&bv[0] = *(const float4*)&Bs[BUF][k][C0]; \
      *(float4*)&bv[4] = *(const float4*)&Bs[BUF][k][C0 + 32]; \
      _Pragma("unroll") \
      for (int i = 0; i < 8; ++i) \
        _Pragma("unroll") \
        for (int j = 0; j < 8; ++j) \
          acc[i][j] += av[i] * bv[j]; \
    } } while (0)

  const int nt = K >> 4;  // 8/16/32/128: even
  GLOADT(0);
  LWRITE(0);
  __syncthreads();
  for (int t = 0; t < nt; t += 2) {
    int k1 = (t + 1) * 16;
    GLOADT(k1);
    COMPT(0);
    LWRITE(1);
    __syncthreads();
    if (t + 2 < nt) {
      int k2 = (t + 2) * 16;
      GLOADT(k2);
      COMPT(1);
      LWRITE(0);
    } else {
      COMPT(1);
    }
    __syncthreads();
  }
#undef GLOADT
#undef LWRITE
#undef COMPT

#pragma unroll
  for (int i = 0; i < 8; ++i) {
    int mr = m0 + (wv & 1) * 64 + ((i < 4) ? (r8 * 4 + i) : (32 + r8 * 4 + i - 4));
#pragma unroll
    for (int jb = 0; jb < 2; ++jb) {
      int nc = n0 + (wv >> 1) * 64 + jb * 32 + c8 * 4;
      float4 o4;
      if (ACC) {
        float4 pv = *(const float4*)(out + (size_t)mr * N + nc);
        o4.x = acc[i][jb * 4 + 0] + pv.x;
        o4.y = acc[i][jb * 4 + 1] + pv.y;
        o4.z = acc[i][jb * 4 + 2] + pv.z;
        o4.w = acc[i][jb * 4 + 3] + pv.w;
      } else {
        float4 bz = *(const float4*)(bias + nc);
        o4.x = acc[i][jb * 4 + 0] + bz.x;
        o4.y = acc[i][jb * 4 + 1] + bz.y;
        o4.z = acc[i][jb * 4 + 2] + bz.z;
        o4.w = acc[i][jb * 4 + 3] + bz.w;
      }
      if (RELU) {
        o4.x = fmaxf(o4.x, 0.f); o4.y = fmaxf(o4.y, 0.f);
        o4.z = fmaxf(o4.z, 0.f); o4.w = fmaxf(o4.w, 0.f);
      }
      *(float4*)(out + (size_t)mr * N + nc) = o4;
    }
  }
}

// ---------------- GEMM (N=256) fused +residual+LayerNorm --------------------
// ACCT0=false: v = acc + bias + xres (Wo path, identical to R11).
// ACCT0=true:  v = acc + tacc + xres (last W2 slice; tacc = running t0).
template<bool ACCT0>
__global__ __launch_bounds__(256) void k_gemm_ln(const float* __restrict__ X,
    const float* __restrict__ W, const float* __restrict__ bias,
    float* __restrict__ xres, const float* __restrict__ tacc,
    const float* __restrict__ lns, const float* __restrict__ lnb,
    int M, int K, int ldw) {
  __shared__ float As[2][16][64];
  __shared__ float Bs[2][16][256];
  const int tid = threadIdx.x;
  const int m0 = blockIdx.x * 64;
  const int tx = tid & 15, ty = tid >> 4;
  const int rowA = tid & 63;
  const int kqA = (tid >> 6) << 2;
  const float* Xp = X + (size_t)(m0 + rowA) * K + kqA;
  const float* Wp = W + (size_t)tid * ldw;

  f32x4 acc[4][4];
#pragma unroll
  for (int r = 0; r < 4; ++r)
#pragma unroll
    for (int q = 0; q < 4; ++q) acc[r][q] = 0.f;

  f32x4 a, b0, b1, b2, b3;

#define GL(KT) do { \
    a  = *(const f32x4*)(Xp + (KT)); \
    b0 = *(const f32x4*)(Wp + (KT));      b1 = *(const f32x4*)(Wp + (KT) + 4); \
    b2 = *(const f32x4*)(Wp + (KT) + 8);  b3 = *(const f32x4*)(Wp + (KT) + 12); } while (0)

#define LW(BUF) do { \
    As[BUF][kqA + 0][rowA] = a[0]; As[BUF][kqA + 1][rowA] = a[1]; \
    As[BUF][kqA + 2][rowA] = a[2]; As[BUF][kqA + 3][rowA] = a[3]; \
    Bs[BUF][ 0][tid] = b0[0]; Bs[BUF][ 1][tid] = b0[1]; \
    Bs[BUF][ 2][tid] = b0[2]; Bs[BUF][ 3][tid] = b0[3]; \
    Bs[BUF][ 4][tid] = b1[0]; Bs[BUF][ 5][tid] = b1[1]; \
    Bs[BUF][ 6][tid] = b1[2]; Bs[BUF][ 7][tid] = b1[3]; \
    Bs[BUF][ 8][tid] = b2[0]; Bs[BUF][ 9][tid] = b2[1]; \
    Bs[BUF][10][tid] = b2[2]; Bs[BUF][11][tid] = b2[3]; \
    Bs[BUF][12][tid] = b3[0]; Bs[BUF][13][tid] = b3[1]; \
    Bs[BUF][14][tid] = b3[2]; Bs[BUF][15][tid] = b3[3]; } while (0)

#define CP(BUF) do { \
    _Pragma("unroll") \
    for (int k = 0; k < 16; ++k) { \
      f32x4 av = *(const f32x4*)&As[BUF][k][ty * 4]; \
      f32x4 bv0 = *(const f32x4*)&Bs[BUF][k][tx * 4]; \
      f32x4 bv1 = *(const f32x4*)&Bs[BUF][k][64 + tx * 4]; \
      f32x4 bv2 = *(const f32x4*)&Bs[BUF][k][128 + tx * 4]; \
      f32x4 bv3 = *(const f32x4*)&Bs[BUF][k][192 + tx * 4]; \
      _Pragma("unroll") \
      for (int r = 0; r < 4; ++r) { \
        acc[r][0] += av[r] * bv0; acc[r][1] += av[r] * bv1; \
        acc[r][2] += av[r] * bv2; acc[r][3] += av[r] * bv3; \
      } \
    } } while (0)

  const int nt = K >> 4;  // 16 (Wo), FW/16 (last W2 slice): even
  GL(0);
  LW(0);
  __syncthreads();
  for (int t = 0; t < nt; t += 2) {
    GL((t + 1) * 16);
    CP(0);
    LW(1);
    __syncthreads();
    if (t + 2 < nt) {
      GL((t + 2) * 16);
      CP(1);
      LW(0);
    } else {
      CP(1);
    }
    __syncthreads();
  }
#undef GL
#undef LW
#undef CP

  f32x4 bza[4], sca[4], lba[4];
#pragma unroll
  for (int q = 0; q < 4; ++q) {
    int c = q * 64 + tx * 4;
    if (!ACCT0) bza[q] = *(const f32x4*)(bias + c);
    sca[q] = *(const f32x4*)(lns + c);
    lba[q] = *(const f32x4*)(lnb + c);
  }
#pragma unroll
  for (int r = 0; r < 4; ++r) {
    size_t row = (size_t)m0 + ty * 4 + r;
    f32x4 v[4];
    float ps = 0.f;
#pragma unroll
    for (int q = 0; q < 4; ++q) {
      f32x4 xr = *(const f32x4*)(xres + row * 256 + q * 64 + tx * 4);
      f32x4 bs;
      if (ACCT0) bs = *(const f32x4*)(tacc + row * 256 + q * 64 + tx * 4);
      else       bs = bza[q];
      v[q] = acc[r][q] + bs + xr;
      ps += v[q][0] + v[q][1] + v[q][2] + v[q][3];
    }
    ps += __shfl_xor(ps, 1); ps += __shfl_xor(ps, 2);
    ps += __shfl_xor(ps, 4); ps += __shfl_xor(ps, 8);
    float mean = ps * (1.f / 256.f);
    float ss = 0.f;
#pragma unroll
    for (int q = 0; q < 4; ++q) {
      v[q] -= mean;
      ss += v[q][0] * v[q][0] + v[q][1] * v[q][1]
          + v[q][2] * v[q][2] + v[q][3] * v[q][3];
    }
    ss += __shfl_xor(ss, 1); ss += __shfl_xor(ss, 2);
    ss += __shfl_xor(ss, 4); ss += __shfl_xor(ss, 8);
    float rs = rsqrtf(ss * (1.f / 256.f) + 1e-5f);
#pragma unroll
    for (int q = 0; q < 4; ++q) {
      f32x4 y = v[q] * rs * sca[q] + lba[q];
      *(f32x4*)(xres + row * 256 + q * 64 + tx * 4) = y;
    }
  }
}

// ---------------- doc attention: block=(batch,head), 256 thr, 1 row/thread --
__global__ __launch_bounds__(256) void k_attn_doc(const float* __restrict__ qkv,
    float* __restrict__ o, int b0) {
  __shared__ f32x4 Ks[256 * 8];
  __shared__ f32x4 Vs[256 * 8];
  int bl = blockIdx.x >> 3, h = blockIdx.x & 7;
  int tid = threadIdx.x;
  const float* base = qkv + (size_t)bl * 256 * 768;
  int hc = h * 32;
  for (int idx = tid; idx < 2048; idx += 256) {
    int s = idx >> 3, w = idx & 7;
    Ks[idx] = *(const f32x4*)(base + (size_t)s * 768 + 256 + hc + w * 4);
    Vs[idx] = *(const f32x4*)(base + (size_t)s * 768 + 512 + hc + w * 4);
  }
  __syncthreads();
  f32x4 q[8], acc[8];
  const float* qp = base + (size_t)tid * 768 + hc;
#pragma unroll
  for (int w = 0; w < 8; ++w) { q[w] = *(const f32x4*)(qp + 4 * w); acc[w] = 0.f; }
  float m = -1e30f, l = 0.f;
  const float scale = 0.17677669529663687f;
  for (int j = 0; j < 256; ++j) {
    const f32x4* kr = &Ks[j * 8];
    f32x4 da = q[0] * kr[0];
    f32x4 db = q[1] * kr[1];
#pragma unroll
    for (int w = 2; w < 8; w += 2) {
      da += q[w] * kr[w];
      db += q[w + 1] * kr[w + 1];
    }
    f32x4 d4 = da + db;
    float s_ = (d4[0] + d4[1] + d4[2] + d4[3]) * scale;
    float mn = fmaxf(m, s_);
    float p = __expf(s_ - mn);
    if (mn > m) {
      float al = __expf(m - mn);
      l *= al;
#pragma unroll
      for (int w = 0; w < 8; ++w) acc[w] *= al;
      m = mn;
    }
    l += p;
    const f32x4* vr = &Vs[j * 8];
#pragma unroll
    for (int w = 0; w < 8; ++w) acc[w] += p * vr[w];
  }
  float inv = 1.f / l;
  float* op = o + ((size_t)(b0 + bl) * 256 + tid) * DMODEL + hc;
#pragma unroll
  for (int w = 0; w < 8; ++w) *(f32x4*)(op + 4 * w) = acc[w] * inv;
}

// ---------------- query attention: block=batch, 256 thr=(head,row) ----------
__global__ __launch_bounds__(256) void k_attn_qry(const float* __restrict__ qkv,
    float* __restrict__ o) {
  __shared__ f32x4 Ks[32 * 64];
  __shared__ f32x4 Vs[32 * 64];
  int bl = blockIdx.x;
  int tid = threadIdx.x;
  const float* base = qkv + (size_t)bl * 32 * 768;
  for (int idx = tid; idx < 2048; idx += 256) {
    int s = idx >> 6, c = idx & 63;
    Ks[idx] = *(const f32x4*)(base + (size_t)s * 768 + 256 + c * 4);
    Vs[idx] = *(const f32x4*)(base + (size_t)s * 768 + 512 + c * 4);
  }
  __syncthreads();
  int h = tid >> 5, row = tid & 31;
  int hc = h * 32;
  f32x4 q[8], acc[8];
  const float* qp = base + (size_t)row * 768 + hc;
#pragma unroll
  for (int w = 0; w < 8; ++w) { q[w] = *(const f32x4*)(qp + 4 * w); acc[w] = 0.f; }
  float m = -1e30f, l = 0.f;
  const float scale = 0.17677669529663687f;
  for (int j = 0; j < 32; ++j) {
    const f32x4* kr = &Ks[j * 64 + h * 8];
    f32x4 da = q[0] * kr[0];
    f32x4 db = q[1] * kr[1];
#pragma unroll
    for (int w = 2; w < 8; w += 2) {
      da += q[w] * kr[w];
      db += q[w + 1] * kr[w + 1];
    }
    f32x4 d4 = da + db;
    float s_ = (d4[0] + d4[1] + d4[2] + d4[3]) * scale;
    float mn = fmaxf(m, s_);
    float p = __expf(s_ - mn);
    if (mn > m) {
      float al = __expf(m - mn);
      l *= al;
#pragma unroll
      for (int w = 0; w < 8; ++w) acc[w] *= al;
      m = mn;
    }
    l += p;
    const f32x4* vr = &Vs[j * 64 + h * 8];
#pragma unroll
    for (int w = 0; w < 8; ++w) acc[w] += p * vr[w];
  }
  float inv = 1.f / l;
  float* op = o + ((size_t)bl * 32 + row) * DMODEL + hc;
#pragma unroll
  for (int w = 0; w < 8; ++w) *(f32x4*)(op + 4 * w) = acc[w] * inv;
}

// ---------------- scoring stage 1: block=(batch, query-half) ----------------
// 16 queries per block, grid 512 (2 blocks/CU). Per-wave qks slots, no
// atomics; partial score (sum over this half's queries) -> part[blk].
__global__ __launch_bounds__(256) void k_score(
    const int* __restrict__ qids, const int* __restrict__ dids,
    const float* __restrict__ emb, const float* __restrict__ xq,
    const float* __restrict__ xd, const float* __restrict__ a_ptr,
    const float* __restrict__ mlp_w, float* __restrict__ part) {
  __shared__ float qmix[16 * 256];
  __shared__ float qks[4][16][11];
  __shared__ float qmask_s[16];
  __shared__ float mw_s[11];
  int blk = blockIdx.x;
  int b = blk >> 1, half = blk & 1;
  int tid = threadIdx.x;
  int wv = tid >> 6, lane = tid & 63;
  float av = a_ptr[0], aw = 1.f - av;
  for (int q = 0; q < 16; ++q) {
    int qg = half * 16 + q;
    int qid = qids[b * 32 + qg];
    float qm = qid > 0 ? 1.f : 0.f;
    float ev = emb[(size_t)qid * 256 + tid];
    float xv = xq[((size_t)b * 32 + qg) * 256 + tid];
    qmix[q * 256 + tid] = (av * ev + aw * xv) * qm;
    if (tid == 0) qmask_s[q] = qm;
  }
  if (tid < 11) mw_s[tid] = mlp_w[tid];
  __syncthreads();
  int j = tid;
  int did = dids[b * 256 + j];
  float dmask = did > 0 ? 1.f : 0.f;
  float sim[16];
#pragma unroll
  for (int q = 0; q < 16; ++q) sim[q] = 0.f;
  const float4* de = (const float4*)(emb + (size_t)did * 256);
  const float4* dxp = (const float4*)(xd + ((size_t)b * 256 + j) * 256);
  for (int c = 0; c < 4; ++c) {
    float4 dreg[16];
#pragma unroll
    for (int w = 0; w < 16; ++w) {
      float4 e = de[c * 16 + w], x = dxp[c * 16 + w];
      dreg[w].x = av * e.x + aw * x.x;
      dreg[w].y = av * e.y + aw * x.y;
      dreg[w].z = av * e.z + aw * x.z;
      dreg[w].w = av * e.w + aw * x.w;
    }
#pragma unroll
    for (int q = 0; q < 16; ++q) {
      const float4* qp = (const float4*)&qmix[q * 256 + c * 64];
      float d_ = 0.f;
#pragma unroll
      for (int w = 0; w < 16; ++w) {
        float4 t = qp[w];
        d_ += t.x * dreg[w].x + t.y * dreg[w].y + t.z * dreg[w].z + t.w * dreg[w].w;
      }
      sim[q] += d_;
    }
  }
  const float MU[11] = {1.f, 0.9f, 0.7f, 0.5f, 0.3f, 0.1f, -0.1f, -0.3f, -0.5f, -0.7f, -0.9f};
  const float IC[11] = {5e7f, 50.f, 50.f, 50.f, 50.f, 50.f, 50.f, 50.f, 50.f, 50.f, 50.f};
  for (int q = 0; q < 16; ++q) {
    float s = sim[q];
    float f = dmask * qmask_s[q];
#pragma unroll
    for (int k = 0; k < 11; ++k) {
      float d_ = s - MU[k];
      float v = expf(-d_ * d_ * IC[k]) * f;
#pragma unroll
      for (int o = 32; o > 0; o >>= 1) v += __shfl_xor(v, o);
      if (lane == 0) qks[wv][q][k] = v;
    }
  }
  __syncthreads();
  if (tid < 176) {
    int q = tid / 11, k = tid - q * 11;
    float kv = (qks[0][q][k] + qks[1][q][k]) + (qks[2][q][k] + qks[3][q][k]);
    qks[0][q][k] = mw_s[k] * (qmask_s[q] * logf(fmaxf(kv, 1e-10f))
                              + kv * (1.f / 256.f));
  }
  __syncthreads();
  if (tid < 16) {
    float p = 0.f;
#pragma unroll
    for (int k = 0; k < 11; ++k) p += qks[0][tid][k];
#pragma unroll
    for (int o = 8; o > 0; o >>= 1) p += __shfl_xor(p, o);
    if (tid == 0) part[blk] = p;
  }
}

// ---------------- scoring stage 2: combine half partials --------------------
__global__ __launch_bounds__(256) void k_score_fin(const float* __restrict__ part,
    float* __restrict__ out) {
  int b = threadIdx.x;
  out[b] = part[2 * b] + part[2 * b + 1];
}

extern "C" void kernel_launch(void* const* d_in, const int* in_sizes, int n_in,
                              void* d_out, int out_size, void* d_ws, size_t ws_size,
                              hipStream_t stream) {
  const int* qids = (const int*)d_in[0];
  const int* dids = (const int*)d_in[1];
  const float* emb = (const float*)d_in[2];
  const float* a = (const float*)d_in[3];
  const float* mlp_w = (const float*)d_in[4];
  const float* Wqkv = (const float*)d_in[5];
  const float* bqkv = (const float*)d_in[6];
  const float* Wo = (const float*)d_in[7];
  const float* bo = (const float*)d_in[8];
  const float* l1s = (const float*)d_in[9];
  const float* l1b = (const float*)d_in[10];
  const float* W1 = (const float*)d_in[11];
  const float* b1 = (const float*)d_in[12];
  const float* W2 = (const float*)d_in[13];
  const float* b2 = (const float*)d_in[14];
  const float* l2s = (const float*)d_in[15];
  const float* l2b = (const float*)d_in[16];
  float* out = (float*)d_out;
  float* ws = (float*)d_ws;

  const int TOK = 73728;                      // 65536 doc + 8192 query tokens
  const size_t QRY_QKV = (size_t)8192 * 768;  // 6.29M floats

  size_t wsf = ws_size / 4;
  const size_t fixed = 2 * (size_t)TOK * 256 + 65536;  // x + t0 + pe
  const int fws[] = {512, 256, 128};
  const int cbs[] = {128, 64, 32};
  int FW = 128, CB = 32;
  for (int i = 0; i < 3; ++i) {
    size_t scr = (size_t)TOK * fws[i];
    size_t sc2 = (size_t)cbs[i] * 196608;
    if (sc2 > scr) scr = sc2;
    if (QRY_QKV > scr) scr = QRY_QKV;
    if (fixed + scr <= wsf) { FW = fws[i]; CB = cbs[i]; break; }
  }

  float* x       = ws;
  float* t0      = x + (size_t)TOK * 256;
  float* pe      = t0 + (size_t)TOK * 256;
  float* scratch = pe + 65536;   // qkv chunk | h_part | score partials

  k_pe<<<256, 256, 0, stream>>>(pe);
  k_embed<<<TOK / 4, 256, 0, stream>>>(dids, qids, emb, pe, x);

  for (int l = 0; l < 2; ++l) {
    const float* wq = Wqkv + (size_t)l * 768 * 256;
    const float* bq = bqkv + l * 768;
    const float* wo = Wo + (size_t)l * 256 * 256;
    const float* bo_ = bo + l * 256;
    const float* w1 = W1 + (size_t)l * 2048 * 256;
    const float* b1_ = b1 + l * 2048;
    const float* w2 = W2 + (size_t)l * 256 * 2048;
    const float* b2_ = b2 + l * 256;

    // doc QKV + attention, chunked by CB batches
    for (int c = 0; c < 256; c += CB) {
      int Mc = CB * 256;
      k_gemm<false, false><<<dim3(6, Mc / 128), 256, 0, stream>>>(
          x + (size_t)c * 65536, wq, bq, scratch, Mc, 768, 256, 256);
      k_attn_doc<<<CB * 8, 256, 0, stream>>>(scratch, t0, c);
    }
    // query QKV + attention
    k_gemm<false, false><<<dim3(6, 64), 256, 0, stream>>>(
        x + (size_t)65536 * 256, wq, bq, scratch, 8192, 768, 256, 256);
    k_attn_qry<<<256, 256, 0, stream>>>(scratch, t0 + (size_t)65536 * 256);
    // Wo + bias + residual + LN1, in-place into x
    k_gemm_ln<false><<<TOK / 64, 256, 0, stream>>>(t0, wo, bo_, x, t0,
        l1s + l * 256, l1b + l * 256, TOK, 256, 256);
    // FFN, ff-sliced; last W2 slice fused with residual+LN2
    int nparts = 2048 / FW;
    for (int p = 0; p < nparts; ++p) {
      k_gemm<true, false><<<dim3(FW / 128 ? FW / 128 : 1, TOK / 128), 256, 0, stream>>>(
          x, w1 + (size_t)p * FW * 256, b1_ + p * FW, scratch, TOK, FW, 256, 256);
      if (p == 0)
        k_gemm<false, false><<<dim3(2, TOK / 128), 256, 0, stream>>>(
            scratch, w2, b2_, t0, TOK, 256, FW, 2048);
      else if (p < nparts - 1)
        k_gemm<false, true><<<dim3(2, TOK / 128), 256, 0, stream>>>(
            scratch, w2 + (size_t)p * FW, b2_, t0, TOK, 256, FW, 2048);
      else
        k_gemm_ln<true><<<TOK / 64, 256, 0, stream>>>(
            scratch, w2 + (size_t)p * FW, b2_, x, t0,
            l2s + l * 256, l2b + l * 256, TOK, FW, 2048);
    }
  }

  // scoring: 2 blocks per batch -> partials -> combine
  float* part = scratch;
  k_score<<<512, 256, 0, stream>>>(qids, dids, emb, x + (size_t)65536 * 256,
                                   x, a, mlp_w, part);
  k_score_fin<<<1, 256, 0, stream>>>(part, out);
}

// Round 13
// 6326.479 us; speedup vs baseline: 2.9347x; 1.0124x over previous
//
#include <hip/hip_runtime.h>
#include <math.h>

// KNRM-style ranker, fp32 end-to-end.
// R13 vs R12 (6.41ms): config/schedule only, kernels unchanged.
//  - FW=256 ff-slices: FFN working set X+h+t0 = 227MB fits the 256MB L3
//    (at FW=512 it was 302MB -> thrash; W2 slices showed FETCH=76MB of
//    h re-reads from HBM). h reads + t0 RMW become L3 hits.
//  - doc-chunk2 QKV merged with query QKV (tokens 32768..73727 contiguous,
//    one M=40960 dispatch; scratch 31.5M floats, total 277MB < 302MB proven).
//  - ws ladder: 277MB (merged) / 252 / 227 / 189MB fallbacks.

#define DMODEL 256
typedef float f32x4 __attribute__((ext_vector_type(4)));

// ---------------- positional-encoding table: pe[s][d], s<256 ----------------
__global__ __launch_bounds__(256) void k_pe(float* __restrict__ pe) {
  int s = blockIdx.x, d = threadIdx.x;
  int i2 = d & ~1;
  float freq = expf((float)i2 * (-9.210340371976184f / 256.f));
  float ang = (float)s * freq;
  pe[s * 256 + d] = (d & 1) ? cosf(ang) : sinf(ang);
}

// ---------------- embed (doc+query merged), 4 tokens / 256-thr block --------
__global__ __launch_bounds__(256) void k_embed(const int* __restrict__ dids,
    const int* __restrict__ qids, const float* __restrict__ emb,
    const float* __restrict__ pe, float* __restrict__ out_x) {
  int tid = threadIdx.x;
  int tok = blockIdx.x * 4 + (tid >> 6);
  int lane = tid & 63;
  int d0 = lane * 4;
  int id, s;
  if (tok < 65536) { id = dids[tok]; s = tok & 255; }
  else             { id = qids[tok - 65536]; s = (tok - 65536) & 31; }
  float m = id > 0 ? 2.f : 0.f;
  float4 e = *(const float4*)(emb + (size_t)id * DMODEL + d0);
  float4 p = *(const float4*)(pe + s * 256 + d0);
  float4 o;
  o.x = m * e.x + p.x; o.y = m * e.y + p.y;
  o.z = m * e.z + p.z; o.w = m * e.w + p.w;
  *(float4*)(out_x + (size_t)tok * DMODEL + d0) = o;
}

// ---------------- fp32 GEMM: out[M,N] = X[M,K] @ W[N,K(ldw)]^T (+bias|+=) ---
template<bool RELU, bool ACC>
__global__ __launch_bounds__(256) void k_gemm(const float* __restrict__ X,
    const float* __restrict__ W, const float* __restrict__ bias,
    float* __restrict__ out, int M, int N, int K, int ldw) {
  __shared__ float As[2][16][128];
  __shared__ float Bs[2][16][128];
  int n0 = blockIdx.x * 128;
  int m0 = blockIdx.y * 128;
  int tid = threadIdx.x;
  const int wv = tid >> 6, lane = tid & 63;
  const int r8 = lane >> 3, c8 = lane & 7;
  const int R0 = (wv & 1) * 64 + r8 * 4;
  const int C0 = (wv >> 1) * 64 + c8 * 4;
  int lr = tid >> 1;
  int lk = (tid & 1) << 3;
  const float* Xp = X + (size_t)(m0 + lr) * K + lk;
  const float* Wp = W + (size_t)(n0 + lr) * ldw + lk;

  float acc[8][8];
#pragma unroll
  for (int i = 0; i < 8; ++i)
#pragma unroll
    for (int j = 0; j < 8; ++j) acc[i][j] = 0.f;

  float4 a0, a1, b0, b1;

#define GLOADT(KT) do { \
    a0 = *(const float4*)(Xp + (KT)); a1 = *(const float4*)(Xp + (KT) + 4); \
    b0 = *(const float4*)(Wp + (KT)); b1 = *(const float4*)(Wp + (KT) + 4); } while (0)

#define LWRITE(BUF) do { \
    As[BUF][lk + 0][lr] = a0.x; As[BUF][lk + 1][lr] = a0.y; \
    As[BUF][lk + 2][lr] = a0.z; As[BUF][lk + 3][lr] = a0.w; \
    As[BUF][lk + 4][lr] = a1.x; As[BUF][lk + 5][lr] = a1.y; \
    As[BUF][lk + 6][lr] = a1.z; As[BUF][lk + 7][lr] = a1.w; \
    Bs[BUF][lk + 0][lr] = b0.x; Bs[BUF][lk + 1][lr] = b0.y; \
    Bs[BUF][lk + 2][lr] = b0.z; Bs[BUF][lk + 3][lr] = b0.w; \
    Bs[BUF][lk + 4][lr] = b1.x; Bs[BUF][lk + 5][lr] = b1.y; \
    Bs[BUF][lk + 6][lr] = b1.z; Bs[BUF][lk + 7][lr] = b1.w; } while (0)

#define COMPT(BUF) do { \
    _Pragma("unroll") \
    for (int k = 0; k < 16; ++k) { \
      float av[8], bv[8]; \
      *(float4*)&av[0] = *(const float4*)&As[BUF][k][R0]; \
      *(float4*)&av[4] = *(const float4*)&As[BUF][k][R0 + 32]; \
      *(float4*)&bv[0] = *(const float4*)&Bs[BUF][k][C0]; \
      *(float4*)&bv[4] = *(const float4*)&Bs[BUF][k][C0 + 32]; \
      _Pragma("unroll") \
      for (int i = 0; i < 8; ++i) \
        _Pragma("unroll") \
        for (int j = 0; j < 8; ++j) \
          acc[i][j] += av[i] * bv[j]; \
    } } while (0)

  const int nt = K >> 4;  // 8/16/32/128: even
  GLOADT(0);
  LWRITE(0);
  __syncthreads();
  for (int t = 0; t < nt; t += 2) {
    int k1 = (t + 1) * 16;
    GLOADT(k1);
    COMPT(0);
    LWRITE(1);
    __syncthreads();
    if (t + 2 < nt) {
      int k2 = (t + 2) * 16;
      GLOADT(k2);
      COMPT(1);
      LWRITE(0);
    } else {
      COMPT(1);
    }
    __syncthreads();
  }
#undef GLOADT
#undef LWRITE
#undef COMPT

#pragma unroll
  for (int i = 0; i < 8; ++i) {
    int mr = m0 + (wv & 1) * 64 + ((i < 4) ? (r8 * 4 + i) : (32 + r8 * 4 + i - 4));
#pragma unroll
    for (int jb = 0; jb < 2; ++jb) {
      int nc = n0 + (wv >> 1) * 64 + jb * 32 + c8 * 4;
      float4 o4;
      if (ACC) {
        float4 pv = *(const float4*)(out + (size_t)mr * N + nc);
        o4.x = acc[i][jb * 4 + 0] + pv.x;
        o4.y = acc[i][jb * 4 + 1] + pv.y;
        o4.z = acc[i][jb * 4 + 2] + pv.z;
        o4.w = acc[i][jb * 4 + 3] + pv.w;
      } else {
        float4 bz = *(const float4*)(bias + nc);
        o4.x = acc[i][jb * 4 + 0] + bz.x;
        o4.y = acc[i][jb * 4 + 1] + bz.y;
        o4.z = acc[i][jb * 4 + 2] + bz.z;
        o4.w = acc[i][jb * 4 + 3] + bz.w;
      }
      if (RELU) {
        o4.x = fmaxf(o4.x, 0.f); o4.y = fmaxf(o4.y, 0.f);
        o4.z = fmaxf(o4.z, 0.f); o4.w = fmaxf(o4.w, 0.f);
      }
      *(float4*)(out + (size_t)mr * N + nc) = o4;
    }
  }
}

// ---------------- GEMM (N=256) fused +residual+LayerNorm --------------------
// ACCT0=false: v = acc + bias + xres (Wo). ACCT0=true: v = acc + tacc + xres.
template<bool ACCT0>
__global__ __launch_bounds__(256) void k_gemm_ln(const float* __restrict__ X,
    const float* __restrict__ W, const float* __restrict__ bias,
    float* __restrict__ xres, const float* __restrict__ tacc,
    const float* __restrict__ lns, const float* __restrict__ lnb,
    int M, int K, int ldw) {
  __shared__ float As[2][16][64];
  __shared__ float Bs[2][16][256];
  const int tid = threadIdx.x;
  const int m0 = blockIdx.x * 64;
  const int tx = tid & 15, ty = tid >> 4;
  const int rowA = tid & 63;
  const int kqA = (tid >> 6) << 2;
  const float* Xp = X + (size_t)(m0 + rowA) * K + kqA;
  const float* Wp = W + (size_t)tid * ldw;

  f32x4 acc[4][4];
#pragma unroll
  for (int r = 0; r < 4; ++r)
#pragma unroll
    for (int q = 0; q < 4; ++q) acc[r][q] = 0.f;

  f32x4 a, b0, b1, b2, b3;

#define GL(KT) do { \
    a  = *(const f32x4*)(Xp + (KT)); \
    b0 = *(const f32x4*)(Wp + (KT));      b1 = *(const f32x4*)(Wp + (KT) + 4); \
    b2 = *(const f32x4*)(Wp + (KT) + 8);  b3 = *(const f32x4*)(Wp + (KT) + 12); } while (0)

#define LW(BUF) do { \
    As[BUF][kqA + 0][rowA] = a[0]; As[BUF][kqA + 1][rowA] = a[1]; \
    As[BUF][kqA + 2][rowA] = a[2]; As[BUF][kqA + 3][rowA] = a[3]; \
    Bs[BUF][ 0][tid] = b0[0]; Bs[BUF][ 1][tid] = b0[1]; \
    Bs[BUF][ 2][tid] = b0[2]; Bs[BUF][ 3][tid] = b0[3]; \
    Bs[BUF][ 4][tid] = b1[0]; Bs[BUF][ 5][tid] = b1[1]; \
    Bs[BUF][ 6][tid] = b1[2]; Bs[BUF][ 7][tid] = b1[3]; \
    Bs[BUF][ 8][tid] = b2[0]; Bs[BUF][ 9][tid] = b2[1]; \
    Bs[BUF][10][tid] = b2[2]; Bs[BUF][11][tid] = b2[3]; \
    Bs[BUF][12][tid] = b3[0]; Bs[BUF][13][tid] = b3[1]; \
    Bs[BUF][14][tid] = b3[2]; Bs[BUF][15][tid] = b3[3]; } while (0)

#define CP(BUF) do { \
    _Pragma("unroll") \
    for (int k = 0; k < 16; ++k) { \
      f32x4 av = *(const f32x4*)&As[BUF][k][ty * 4]; \
      f32x4 bv0 = *(const f32x4*)&Bs[BUF][k][tx * 4]; \
      f32x4 bv1 = *(const f32x4*)&Bs[BUF][k][64 + tx * 4]; \
      f32x4 bv2 = *(const f32x4*)&Bs[BUF][k][128 + tx * 4]; \
      f32x4 bv3 = *(const f32x4*)&Bs[BUF][k][192 + tx * 4]; \
      _Pragma("unroll") \
      for (int r = 0; r < 4; ++r) { \
        acc[r][0] += av[r] * bv0; acc[r][1] += av[r] * bv1; \
        acc[r][2] += av[r] * bv2; acc[r][3] += av[r] * bv3; \
      } \
    } } while (0)

  const int nt = K >> 4;
  GL(0);
  LW(0);
  __syncthreads();
  for (int t = 0; t < nt; t += 2) {
    GL((t + 1) * 16);
    CP(0);
    LW(1);
    __syncthreads();
    if (t + 2 < nt) {
      GL((t + 2) * 16);
      CP(1);
      LW(0);
    } else {
      CP(1);
    }
    __syncthreads();
  }
#undef GL
#undef LW
#undef CP

  f32x4 bza[4], sca[4], lba[4];
#pragma unroll
  for (int q = 0; q < 4; ++q) {
    int c = q * 64 + tx * 4;
    if (!ACCT0) bza[q] = *(const f32x4*)(bias + c);
    sca[q] = *(const f32x4*)(lns + c);
    lba[q] = *(const f32x4*)(lnb + c);
  }
#pragma unroll
  for (int r = 0; r < 4; ++r) {
    size_t row = (size_t)m0 + ty * 4 + r;
    f32x4 v[4];
    float ps = 0.f;
#pragma unroll
    for (int q = 0; q < 4; ++q) {
      f32x4 xr = *(const f32x4*)(xres + row * 256 + q * 64 + tx * 4);
      f32x4 bs;
      if (ACCT0) bs = *(const f32x4*)(tacc + row * 256 + q * 64 + tx * 4);
      else       bs = bza[q];
      v[q] = acc[r][q] + bs + xr;
      ps += v[q][0] + v[q][1] + v[q][2] + v[q][3];
    }
    ps += __shfl_xor(ps, 1); ps += __shfl_xor(ps, 2);
    ps += __shfl_xor(ps, 4); ps += __shfl_xor(ps, 8);
    float mean = ps * (1.f / 256.f);
    float ss = 0.f;
#pragma unroll
    for (int q = 0; q < 4; ++q) {
      v[q] -= mean;
      ss += v[q][0] * v[q][0] + v[q][1] * v[q][1]
          + v[q][2] * v[q][2] + v[q][3] * v[q][3];
    }
    ss += __shfl_xor(ss, 1); ss += __shfl_xor(ss, 2);
    ss += __shfl_xor(ss, 4); ss += __shfl_xor(ss, 8);
    float rs = rsqrtf(ss * (1.f / 256.f) + 1e-5f);
#pragma unroll
    for (int q = 0; q < 4; ++q) {
      f32x4 y = v[q] * rs * sca[q] + lba[q];
      *(f32x4*)(xres + row * 256 + q * 64 + tx * 4) = y;
    }
  }
}

// ---------------- doc attention: block=(batch,head), 256 thr, 1 row/thread --
__global__ __launch_bounds__(256) void k_attn_doc(const float* __restrict__ qkv,
    float* __restrict__ o, int b0) {
  __shared__ f32x4 Ks[256 * 8];
  __shared__ f32x4 Vs[256 * 8];
  int bl = blockIdx.x >> 3, h = blockIdx.x & 7;
  int tid = threadIdx.x;
  const float* base = qkv + (size_t)bl * 256 * 768;
  int hc = h * 32;
  for (int idx = tid; idx < 2048; idx += 256) {
    int s = idx >> 3, w = idx & 7;
    Ks[idx] = *(const f32x4*)(base + (size_t)s * 768 + 256 + hc + w * 4);
    Vs[idx] = *(const f32x4*)(base + (size_t)s * 768 + 512 + hc + w * 4);
  }
  __syncthreads();
  f32x4 q[8], acc[8];
  const float* qp = base + (size_t)tid * 768 + hc;
#pragma unroll
  for (int w = 0; w < 8; ++w) { q[w] = *(const f32x4*)(qp + 4 * w); acc[w] = 0.f; }
  float m = -1e30f, l = 0.f;
  const float scale = 0.17677669529663687f;
  for (int j = 0; j < 256; ++j) {
    const f32x4* kr = &Ks[j * 8];
    f32x4 da = q[0] * kr[0];
    f32x4 db = q[1] * kr[1];
#pragma unroll
    for (int w = 2; w < 8; w += 2) {
      da += q[w] * kr[w];
      db += q[w + 1] * kr[w + 1];
    }
    f32x4 d4 = da + db;
    float s_ = (d4[0] + d4[1] + d4[2] + d4[3]) * scale;
    float mn = fmaxf(m, s_);
    float p = __expf(s_ - mn);
    if (mn > m) {
      float al = __expf(m - mn);
      l *= al;
#pragma unroll
      for (int w = 0; w < 8; ++w) acc[w] *= al;
      m = mn;
    }
    l += p;
    const f32x4* vr = &Vs[j * 8];
#pragma unroll
    for (int w = 0; w < 8; ++w) acc[w] += p * vr[w];
  }
  float inv = 1.f / l;
  float* op = o + ((size_t)(b0 + bl) * 256 + tid) * DMODEL + hc;
#pragma unroll
  for (int w = 0; w < 8; ++w) *(f32x4*)(op + 4 * w) = acc[w] * inv;
}

// ---------------- query attention: block=batch, 256 thr=(head,row) ----------
__global__ __launch_bounds__(256) void k_attn_qry(const float* __restrict__ qkv,
    float* __restrict__ o) {
  __shared__ f32x4 Ks[32 * 64];
  __shared__ f32x4 Vs[32 * 64];
  int bl = blockIdx.x;
  int tid = threadIdx.x;
  const float* base = qkv + (size_t)bl * 32 * 768;
  for (int idx = tid; idx < 2048; idx += 256) {
    int s = idx >> 6, c = idx & 63;
    Ks[idx] = *(const f32x4*)(base + (size_t)s * 768 + 256 + c * 4);
    Vs[idx] = *(const f32x4*)(base + (size_t)s * 768 + 512 + c * 4);
  }
  __syncthreads();
  int h = tid >> 5, row = tid & 31;
  int hc = h * 32;
  f32x4 q[8], acc[8];
  const float* qp = base + (size_t)row * 768 + hc;
#pragma unroll
  for (int w = 0; w < 8; ++w) { q[w] = *(const f32x4*)(qp + 4 * w); acc[w] = 0.f; }
  float m = -1e30f, l = 0.f;
  const float scale = 0.17677669529663687f;
  for (int j = 0; j < 32; ++j) {
    const f32x4* kr = &Ks[j * 64 + h * 8];
    f32x4 da = q[0] * kr[0];
    f32x4 db = q[1] * kr[1];
#pragma unroll
    for (int w = 2; w < 8; w += 2) {
      da += q[w] * kr[w];
      db += q[w + 1] * kr[w + 1];
    }
    f32x4 d4 = da + db;
    float s_ = (d4[0] + d4[1] + d4[2] + d4[3]) * scale;
    float mn = fmaxf(m, s_);
    float p = __expf(s_ - mn);
    if (mn > m) {
      float al = __expf(m - mn);
      l *= al;
#pragma unroll
      for (int w = 0; w < 8; ++w) acc[w] *= al;
      m = mn;
    }
    l += p;
    const f32x4* vr = &Vs[j * 64 + h * 8];
#pragma unroll
    for (int w = 0; w < 8; ++w) acc[w] += p * vr[w];
  }
  float inv = 1.f / l;
  float* op = o + ((size_t)bl * 32 + row) * DMODEL + hc;
#pragma unroll
  for (int w = 0; w < 8; ++w) *(f32x4*)(op + 4 * w) = acc[w] * inv;
}

// ---------------- scoring stage 1: block=(batch, query-half) ----------------
__global__ __launch_bounds__(256) void k_score(
    const int* __restrict__ qids, const int* __restrict__ dids,
    const float* __restrict__ emb, const float* __restrict__ xq,
    const float* __restrict__ xd, const float* __restrict__ a_ptr,
    const float* __restrict__ mlp_w, float* __restrict__ part) {
  __shared__ float qmix[16 * 256];
  __shared__ float qks[4][16][11];
  __shared__ float qmask_s[16];
  __shared__ float mw_s[11];
  int blk = blockIdx.x;
  int b = blk >> 1, half = blk & 1;
  int tid = threadIdx.x;
  int wv = tid >> 6, lane = tid & 63;
  float av = a_ptr[0], aw = 1.f - av;
  for (int q = 0; q < 16; ++q) {
    int qg = half * 16 + q;
    int qid = qids[b * 32 + qg];
    float qm = qid > 0 ? 1.f : 0.f;
    float ev = emb[(size_t)qid * 256 + tid];
    float xv = xq[((size_t)b * 32 + qg) * 256 + tid];
    qmix[q * 256 + tid] = (av * ev + aw * xv) * qm;
    if (tid == 0) qmask_s[q] = qm;
  }
  if (tid < 11) mw_s[tid] = mlp_w[tid];
  __syncthreads();
  int j = tid;
  int did = dids[b * 256 + j];
  float dmask = did > 0 ? 1.f : 0.f;
  float sim[16];
#pragma unroll
  for (int q = 0; q < 16; ++q) sim[q] = 0.f;
  const float4* de = (const float4*)(emb + (size_t)did * 256);
  const float4* dxp = (const float4*)(xd + ((size_t)b * 256 + j) * 256);
  for (int c = 0; c < 4; ++c) {
    float4 dreg[16];
#pragma unroll
    for (int w = 0; w < 16; ++w) {
      float4 e = de[c * 16 + w], x = dxp[c * 16 + w];
      dreg[w].x = av * e.x + aw * x.x;
      dreg[w].y = av * e.y + aw * x.y;
      dreg[w].z = av * e.z + aw * x.z;
      dreg[w].w = av * e.w + aw * x.w;
    }
#pragma unroll
    for (int q = 0; q < 16; ++q) {
      const float4* qp = (const float4*)&qmix[q * 256 + c * 64];
      float d_ = 0.f;
#pragma unroll
      for (int w = 0; w < 16; ++w) {
        float4 t = qp[w];
        d_ += t.x * dreg[w].x + t.y * dreg[w].y + t.z * dreg[w].z + t.w * dreg[w].w;
      }
      sim[q] += d_;
    }
  }
  const float MU[11] = {1.f, 0.9f, 0.7f, 0.5f, 0.3f, 0.1f, -0.1f, -0.3f, -0.5f, -0.7f, -0.9f};
  const float IC[11] = {5e7f, 50.f, 50.f, 50.f, 50.f, 50.f, 50.f, 50.f, 50.f, 50.f, 50.f};
  for (int q = 0; q < 16; ++q) {
    float s = sim[q];
    float f = dmask * qmask_s[q];
#pragma unroll
    for (int k = 0; k < 11; ++k) {
      float d_ = s - MU[k];
      float v = expf(-d_ * d_ * IC[k]) * f;
#pragma unroll
      for (int o = 32; o > 0; o >>= 1) v += __shfl_xor(v, o);
      if (lane == 0) qks[wv][q][k] = v;
    }
  }
  __syncthreads();
  if (tid < 176) {
    int q = tid / 11, k = tid - q * 11;
    float kv = (qks[0][q][k] + qks[1][q][k]) + (qks[2][q][k] + qks[3][q][k]);
    qks[0][q][k] = mw_s[k] * (qmask_s[q] * logf(fmaxf(kv, 1e-10f))
                              + kv * (1.f / 256.f));
  }
  __syncthreads();
  if (tid < 16) {
    float p = 0.f;
#pragma unroll
    for (int k = 0; k < 11; ++k) p += qks[0][tid][k];
#pragma unroll
    for (int o = 8; o > 0; o >>= 1) p += __shfl_xor(p, o);
    if (tid == 0) part[blk] = p;
  }
}

// ---------------- scoring stage 2: combine half partials --------------------
__global__ __launch_bounds__(256) void k_score_fin(const float* __restrict__ part,
    float* __restrict__ out) {
  int b = threadIdx.x;
  out[b] = part[2 * b] + part[2 * b + 1];
}

extern "C" void kernel_launch(void* const* d_in, const int* in_sizes, int n_in,
                              void* d_out, int out_size, void* d_ws, size_t ws_size,
                              hipStream_t stream) {
  const int* qids = (const int*)d_in[0];
  const int* dids = (const int*)d_in[1];
  const float* emb = (const float*)d_in[2];
  const float* a = (const float*)d_in[3];
  const float* mlp_w = (const float*)d_in[4];
  const float* Wqkv = (const float*)d_in[5];
  const float* bqkv = (const float*)d_in[6];
  const float* Wo = (const float*)d_in[7];
  const float* bo = (const float*)d_in[8];
  const float* l1s = (const float*)d_in[9];
  const float* l1b = (const float*)d_in[10];
  const float* W1 = (const float*)d_in[11];
  const float* b1 = (const float*)d_in[12];
  const float* W2 = (const float*)d_in[13];
  const float* b2 = (const float*)d_in[14];
  const float* l2s = (const float*)d_in[15];
  const float* l2b = (const float*)d_in[16];
  float* out = (float*)d_out;
  float* ws = (float*)d_ws;

  const int TOK = 73728;                      // 65536 doc + 8192 query tokens
  size_t wsf = ws_size / 4;
  const size_t fixed = 2 * (size_t)TOK * 256 + 65536;  // x + t0 + pe

  // rungs: (merged-QKV 31.46M | CB=128 25.17M | CB=64 18.87M | CB=32,FW=128)
  int FW = 128, CB = 32;
  bool merged = false;
  size_t scrN;
  if (fixed + (size_t)40960 * 768 <= wsf) {
    merged = true; FW = 256; CB = 128; scrN = (size_t)40960 * 768;        // 277MB
  } else if (fixed + (size_t)128 * 196608 <= wsf) {
    FW = 256; CB = 128; scrN = (size_t)128 * 196608;                       // 252MB
  } else if (fixed + (size_t)TOK * 256 <= wsf) {
    FW = 256; CB = 64; scrN = (size_t)TOK * 256;                           // 227MB
  } else {
    FW = 128; CB = 32; scrN = (size_t)TOK * 128;                           // 189MB
  }
  (void)scrN;

  float* x       = ws;
  float* t0      = x + (size_t)TOK * 256;
  float* pe      = t0 + (size_t)TOK * 256;
  float* scratch = pe + 65536;   // qkv chunk | h_part | score partials

  k_pe<<<256, 256, 0, stream>>>(pe);
  k_embed<<<TOK / 4, 256, 0, stream>>>(dids, qids, emb, pe, x);

  for (int l = 0; l < 2; ++l) {
    const float* wq = Wqkv + (size_t)l * 768 * 256;
    const float* bq = bqkv + l * 768;
    const float* wo = Wo + (size_t)l * 256 * 256;
    const float* bo_ = bo + l * 256;
    const float* w1 = W1 + (size_t)l * 2048 * 256;
    const float* b1_ = b1 + l * 2048;
    const float* w2 = W2 + (size_t)l * 256 * 2048;
    const float* b2_ = b2 + l * 256;

    if (merged) {
      // chunk 1: doc batches 0..127
      k_gemm<false, false><<<dim3(6, 256), 256, 0, stream>>>(
          x, wq, bq, scratch, 32768, 768, 256, 256);
      k_attn_doc<<<1024, 256, 0, stream>>>(scratch, t0, 0);
      // chunk 2: doc batches 128..255 + all query tokens (contiguous 40960)
      k_gemm<false, false><<<dim3(6, 320), 256, 0, stream>>>(
          x + (size_t)32768 * 256, wq, bq, scratch, 40960, 768, 256, 256);
      k_attn_doc<<<1024, 256, 0, stream>>>(scratch, t0, 128);
      k_attn_qry<<<256, 256, 0, stream>>>(scratch + (size_t)32768 * 768,
                                          t0 + (size_t)65536 * 256);
    } else {
      for (int c = 0; c < 256; c += CB) {
        int Mc = CB * 256;
        k_gemm<false, false><<<dim3(6, Mc / 128), 256, 0, stream>>>(
            x + (size_t)c * 65536, wq, bq, scratch, Mc, 768, 256, 256);
        k_attn_doc<<<CB * 8, 256, 0, stream>>>(scratch, t0, c);
      }
      k_gemm<false, false><<<dim3(6, 64), 256, 0, stream>>>(
          x + (size_t)65536 * 256, wq, bq, scratch, 8192, 768, 256, 256);
      k_attn_qry<<<256, 256, 0, stream>>>(scratch, t0 + (size_t)65536 * 256);
    }
    // Wo + bias + residual + LN1, in-place into x
    k_gemm_ln<false><<<TOK / 64, 256, 0, stream>>>(t0, wo, bo_, x, t0,
        l1s + l * 256, l1b + l * 256, TOK, 256, 256);
    // FFN, ff-sliced (FW); last W2 slice fused with residual+LN2
    int nparts = 2048 / FW;
    for (int p = 0; p < nparts; ++p) {
      k_gemm<true, false><<<dim3(FW / 128, TOK / 128), 256, 0, stream>>>(
          x, w1 + (size_t)p * FW * 256, b1_ + p * FW, scratch, TOK, FW, 256, 256);
      if (p == 0)
        k_gemm<false, false><<<dim3(2, TOK / 128), 256, 0, stream>>>(
            scratch, w2, b2_, t0, TOK, 256, FW, 2048);
      else if (p < nparts - 1)
        k_gemm<false, true><<<dim3(2, TOK / 128), 256, 0, stream>>>(
            scratch, w2 + (size_t)p * FW, b2_, t0, TOK, 256, FW, 2048);
      else
        k_gemm_ln<true><<<TOK / 64, 256, 0, stream>>>(
            scratch, w2 + (size_t)p * FW, b2_, x, t0,
            l2s + l * 256, l2b + l * 256, TOK, FW, 2048);
    }
  }

  // scoring: 2 blocks per batch -> partials -> combine
  float* part = scratch;
  k_score<<<512, 256, 0, stream>>>(qids, dids, emb, x + (size_t)65536 * 256,
                                   x, a, mlp_w, part);
  k_score_fin<<<1, 256, 0, stream>>>(part, out);
}

// Round 14
// 6252.835 us; speedup vs baseline: 2.9692x; 1.0118x over previous
//
#include <hip/hip_runtime.h>
#include <math.h>

// KNRM-style ranker, fp32 end-to-end.
// R14 vs R13 (6.33ms): k_attn_doc only; all else verbatim R13.
//  - K/V processed in 2 halves of 128 keys: LDS 64KB -> 32KB => 5 blocks/CU
//    (20 waves) vs 2 (8 waves). R13 counters: Occ 21%, VALUBusy 50% --
//    latency-bound on the serial dot->hadd->exp chain at 2 waves/SIMD.
//  - j-unroll x2: two independent dot chains per iteration, one rescale per
//    pair, PV 16 independent vec-FMAs => ~2x per-thread ILP.

#define DMODEL 256
typedef float f32x4 __attribute__((ext_vector_type(4)));

// ---------------- positional-encoding table: pe[s][d], s<256 ----------------
__global__ __launch_bounds__(256) void k_pe(float* __restrict__ pe) {
  int s = blockIdx.x, d = threadIdx.x;
  int i2 = d & ~1;
  float freq = expf((float)i2 * (-9.210340371976184f / 256.f));
  float ang = (float)s * freq;
  pe[s * 256 + d] = (d & 1) ? cosf(ang) : sinf(ang);
}

// ---------------- embed (doc+query merged), 4 tokens / 256-thr block --------
__global__ __launch_bounds__(256) void k_embed(const int* __restrict__ dids,
    const int* __restrict__ qids, const float* __restrict__ emb,
    const float* __restrict__ pe, float* __restrict__ out_x) {
  int tid = threadIdx.x;
  int tok = blockIdx.x * 4 + (tid >> 6);
  int lane = tid & 63;
  int d0 = lane * 4;
  int id, s;
  if (tok < 65536) { id = dids[tok]; s = tok & 255; }
  else             { id = qids[tok - 65536]; s = (tok - 65536) & 31; }
  float m = id > 0 ? 2.f : 0.f;
  float4 e = *(const float4*)(emb + (size_t)id * DMODEL + d0);
  float4 p = *(const float4*)(pe + s * 256 + d0);
  float4 o;
  o.x = m * e.x + p.x; o.y = m * e.y + p.y;
  o.z = m * e.z + p.z; o.w = m * e.w + p.w;
  *(float4*)(out_x + (size_t)tok * DMODEL + d0) = o;
}

// ---------------- fp32 GEMM: out[M,N] = X[M,K] @ W[N,K(ldw)]^T (+bias|+=) ---
template<bool RELU, bool ACC>
__global__ __launch_bounds__(256) void k_gemm(const float* __restrict__ X,
    const float* __restrict__ W, const float* __restrict__ bias,
    float* __restrict__ out, int M, int N, int K, int ldw) {
  __shared__ float As[2][16][128];
  __shared__ float Bs[2][16][128];
  int n0 = blockIdx.x * 128;
  int m0 = blockIdx.y * 128;
  int tid = threadIdx.x;
  const int wv = tid >> 6, lane = tid & 63;
  const int r8 = lane >> 3, c8 = lane & 7;
  const int R0 = (wv & 1) * 64 + r8 * 4;
  const int C0 = (wv >> 1) * 64 + c8 * 4;
  int lr = tid >> 1;
  int lk = (tid & 1) << 3;
  const float* Xp = X + (size_t)(m0 + lr) * K + lk;
  const float* Wp = W + (size_t)(n0 + lr) * ldw + lk;

  float acc[8][8];
#pragma unroll
  for (int i = 0; i < 8; ++i)
#pragma unroll
    for (int j = 0; j < 8; ++j) acc[i][j] = 0.f;

  float4 a0, a1, b0, b1;

#define GLOADT(KT) do { \
    a0 = *(const float4*)(Xp + (KT)); a1 = *(const float4*)(Xp + (KT) + 4); \
    b0 = *(const float4*)(Wp + (KT)); b1 = *(const float4*)(Wp + (KT) + 4); } while (0)

#define LWRITE(BUF) do { \
    As[BUF][lk + 0][lr] = a0.x; As[BUF][lk + 1][lr] = a0.y; \
    As[BUF][lk + 2][lr] = a0.z; As[BUF][lk + 3][lr] = a0.w; \
    As[BUF][lk + 4][lr] = a1.x; As[BUF][lk + 5][lr] = a1.y; \
    As[BUF][lk + 6][lr] = a1.z; As[BUF][lk + 7][lr] = a1.w; \
    Bs[BUF][lk + 0][lr] = b0.x; Bs[BUF][lk + 1][lr] = b0.y; \
    Bs[BUF][lk + 2][lr] = b0.z; Bs[BUF][lk + 3][lr] = b0.w; \
    Bs[BUF][lk + 4][lr] = b1.x; Bs[BUF][lk + 5][lr] = b1.y; \
    Bs[BUF][lk + 6][lr] = b1.z; Bs[BUF][lk + 7][lr] = b1.w; } while (0)

#define COMPT(BUF) do { \
    _Pragma("unroll") \
    for (int k = 0; k < 16; ++k) { \
      float av[8], bv[8]; \
      *(float4*)&av[0] = *(const float4*)&As[BUF][k][R0]; \
      *(float4*)&av[4] = *(const float4*)&As[BUF][k][R0 + 32]; \
      *(float4*)&bv[0] = *(const float4*)&Bs[BUF][k][C0]; \
      *(float4*)&bv[4] = *(const float4*)&Bs[BUF][k][C0 + 32]; \
      _Pragma("unroll") \
      for (int i = 0; i < 8; ++i) \
        _Pragma("unroll") \
        for (int j = 0; j < 8; ++j) \
          acc[i][j] += av[i] * bv[j]; \
    } } while (0)

  const int nt = K >> 4;  // 8/16/32/128: even
  GLOADT(0);
  LWRITE(0);
  __syncthreads();
  for (int t = 0; t < nt; t += 2) {
    int k1 = (t + 1) * 16;
    GLOADT(k1);
    COMPT(0);
    LWRITE(1);
    __syncthreads();
    if (t + 2 < nt) {
      int k2 = (t + 2) * 16;
      GLOADT(k2);
      COMPT(1);
      LWRITE(0);
    } else {
      COMPT(1);
    }
    __syncthreads();
  }
#undef GLOADT
#undef LWRITE
#undef COMPT

#pragma unroll
  for (int i = 0; i < 8; ++i) {
    int mr = m0 + (wv & 1) * 64 + ((i < 4) ? (r8 * 4 + i) : (32 + r8 * 4 + i - 4));
#pragma unroll
    for (int jb = 0; jb < 2; ++jb) {
      int nc = n0 + (wv >> 1) * 64 + jb * 32 + c8 * 4;
      float4 o4;
      if (ACC) {
        float4 pv = *(const float4*)(out + (size_t)mr * N + nc);
        o4.x = acc[i][jb * 4 + 0] + pv.x;
        o4.y = acc[i][jb * 4 + 1] + pv.y;
        o4.z = acc[i][jb * 4 + 2] + pv.z;
        o4.w = acc[i][jb * 4 + 3] + pv.w;
      } else {
        float4 bz = *(const float4*)(bias + nc);
        o4.x = acc[i][jb * 4 + 0] + bz.x;
        o4.y = acc[i][jb * 4 + 1] + bz.y;
        o4.z = acc[i][jb * 4 + 2] + bz.z;
        o4.w = acc[i][jb * 4 + 3] + bz.w;
      }
      if (RELU) {
        o4.x = fmaxf(o4.x, 0.f); o4.y = fmaxf(o4.y, 0.f);
        o4.z = fmaxf(o4.z, 0.f); o4.w = fmaxf(o4.w, 0.f);
      }
      *(float4*)(out + (size_t)mr * N + nc) = o4;
    }
  }
}

// ---------------- GEMM (N=256) fused +residual+LayerNorm --------------------
template<bool ACCT0>
__global__ __launch_bounds__(256) void k_gemm_ln(const float* __restrict__ X,
    const float* __restrict__ W, const float* __restrict__ bias,
    float* __restrict__ xres, const float* __restrict__ tacc,
    const float* __restrict__ lns, const float* __restrict__ lnb,
    int M, int K, int ldw) {
  __shared__ float As[2][16][64];
  __shared__ float Bs[2][16][256];
  const int tid = threadIdx.x;
  const int m0 = blockIdx.x * 64;
  const int tx = tid & 15, ty = tid >> 4;
  const int rowA = tid & 63;
  const int kqA = (tid >> 6) << 2;
  const float* Xp = X + (size_t)(m0 + rowA) * K + kqA;
  const float* Wp = W + (size_t)tid * ldw;

  f32x4 acc[4][4];
#pragma unroll
  for (int r = 0; r < 4; ++r)
#pragma unroll
    for (int q = 0; q < 4; ++q) acc[r][q] = 0.f;

  f32x4 a, b0, b1, b2, b3;

#define GL(KT) do { \
    a  = *(const f32x4*)(Xp + (KT)); \
    b0 = *(const f32x4*)(Wp + (KT));      b1 = *(const f32x4*)(Wp + (KT) + 4); \
    b2 = *(const f32x4*)(Wp + (KT) + 8);  b3 = *(const f32x4*)(Wp + (KT) + 12); } while (0)

#define LW(BUF) do { \
    As[BUF][kqA + 0][rowA] = a[0]; As[BUF][kqA + 1][rowA] = a[1]; \
    As[BUF][kqA + 2][rowA] = a[2]; As[BUF][kqA + 3][rowA] = a[3]; \
    Bs[BUF][ 0][tid] = b0[0]; Bs[BUF][ 1][tid] = b0[1]; \
    Bs[BUF][ 2][tid] = b0[2]; Bs[BUF][ 3][tid] = b0[3]; \
    Bs[BUF][ 4][tid] = b1[0]; Bs[BUF][ 5][tid] = b1[1]; \
    Bs[BUF][ 6][tid] = b1[2]; Bs[BUF][ 7][tid] = b1[3]; \
    Bs[BUF][ 8][tid] = b2[0]; Bs[BUF][ 9][tid] = b2[1]; \
    Bs[BUF][10][tid] = b2[2]; Bs[BUF][11][tid] = b2[3]; \
    Bs[BUF][12][tid] = b3[0]; Bs[BUF][13][tid] = b3[1]; \
    Bs[BUF][14][tid] = b3[2]; Bs[BUF][15][tid] = b3[3]; } while (0)

#define CP(BUF) do { \
    _Pragma("unroll") \
    for (int k = 0; k < 16; ++k) { \
      f32x4 av = *(const f32x4*)&As[BUF][k][ty * 4]; \
      f32x4 bv0 = *(const f32x4*)&Bs[BUF][k][tx * 4]; \
      f32x4 bv1 = *(const f32x4*)&Bs[BUF][k][64 + tx * 4]; \
      f32x4 bv2 = *(const f32x4*)&Bs[BUF][k][128 + tx * 4]; \
      f32x4 bv3 = *(const f32x4*)&Bs[BUF][k][192 + tx * 4]; \
      _Pragma("unroll") \
      for (int r = 0; r < 4; ++r) { \
        acc[r][0] += av[r] * bv0; acc[r][1] += av[r] * bv1; \
        acc[r][2] += av[r] * bv2; acc[r][3] += av[r] * bv3; \
      } \
    } } while (0)

  const int nt = K >> 4;
  GL(0);
  LW(0);
  __syncthreads();
  for (int t = 0; t < nt; t += 2) {
    GL((t + 1) * 16);
    CP(0);
    LW(1);
    __syncthreads();
    if (t + 2 < nt) {
      GL((t + 2) * 16);
      CP(1);
      LW(0);
    } else {
      CP(1);
    }
    __syncthreads();
  }
#undef GL
#undef LW
#undef CP

  f32x4 bza[4], sca[4], lba[4];
#pragma unroll
  for (int q = 0; q < 4; ++q) {
    int c = q * 64 + tx * 4;
    if (!ACCT0) bza[q] = *(const f32x4*)(bias + c);
    sca[q] = *(const f32x4*)(lns + c);
    lba[q] = *(const f32x4*)(lnb + c);
  }
#pragma unroll
  for (int r = 0; r < 4; ++r) {
    size_t row = (size_t)m0 + ty * 4 + r;
    f32x4 v[4];
    float ps = 0.f;
#pragma unroll
    for (int q = 0; q < 4; ++q) {
      f32x4 xr = *(const f32x4*)(xres + row * 256 + q * 64 + tx * 4);
      f32x4 bs;
      if (ACCT0) bs = *(const f32x4*)(tacc + row * 256 + q * 64 + tx * 4);
      else       bs = bza[q];
      v[q] = acc[r][q] + bs + xr;
      ps += v[q][0] + v[q][1] + v[q][2] + v[q][3];
    }
    ps += __shfl_xor(ps, 1); ps += __shfl_xor(ps, 2);
    ps += __shfl_xor(ps, 4); ps += __shfl_xor(ps, 8);
    float mean = ps * (1.f / 256.f);
    float ss = 0.f;
#pragma unroll
    for (int q = 0; q < 4; ++q) {
      v[q] -= mean;
      ss += v[q][0] * v[q][0] + v[q][1] * v[q][1]
          + v[q][2] * v[q][2] + v[q][3] * v[q][3];
    }
    ss += __shfl_xor(ss, 1); ss += __shfl_xor(ss, 2);
    ss += __shfl_xor(ss, 4); ss += __shfl_xor(ss, 8);
    float rs = rsqrtf(ss * (1.f / 256.f) + 1e-5f);
#pragma unroll
    for (int q = 0; q < 4; ++q) {
      f32x4 y = v[q] * rs * sca[q] + lba[q];
      *(f32x4*)(xres + row * 256 + q * 64 + tx * 4) = y;
    }
  }
}

// ---------------- doc attention: 2 key-halves in LDS (32KB), j-unroll x2 ----
__global__ __launch_bounds__(256) void k_attn_doc(const float* __restrict__ qkv,
    float* __restrict__ o, int b0) {
  __shared__ f32x4 Ks[128 * 8];
  __shared__ f32x4 Vs[128 * 8];
  int bl = blockIdx.x >> 3, h = blockIdx.x & 7;
  int tid = threadIdx.x;
  const float* base = qkv + (size_t)bl * 256 * 768;
  int hc = h * 32;
  f32x4 q[8], acc[8];
  const float* qp = base + (size_t)tid * 768 + hc;
#pragma unroll
  for (int w = 0; w < 8; ++w) { q[w] = *(const f32x4*)(qp + 4 * w); acc[w] = 0.f; }
  float m = -1e30f, l = 0.f;
  const float scale = 0.17677669529663687f;

  for (int half = 0; half < 2; ++half) {
    if (half) __syncthreads();               // prior compute done before reuse
    for (int idx = tid; idx < 1024; idx += 256) {
      int s = idx >> 3, w = idx & 7;
      const float* kb = base + (size_t)(half * 128 + s) * 768;
      Ks[idx] = *(const f32x4*)(kb + 256 + hc + w * 4);
      Vs[idx] = *(const f32x4*)(kb + 512 + hc + w * 4);
    }
    __syncthreads();
    for (int j = 0; j < 128; j += 2) {
      const f32x4* kr0 = &Ks[j * 8];
      const f32x4* kr1 = &Ks[(j + 1) * 8];
      f32x4 da0 = q[0] * kr0[0], db0 = q[1] * kr0[1];
      f32x4 da1 = q[0] * kr1[0], db1 = q[1] * kr1[1];
#pragma unroll
      for (int w = 2; w < 8; w += 2) {
        da0 += q[w] * kr0[w];     db0 += q[w + 1] * kr0[w + 1];
        da1 += q[w] * kr1[w];     db1 += q[w + 1] * kr1[w + 1];
      }
      f32x4 d40 = da0 + db0, d41 = da1 + db1;
      float s0 = (d40[0] + d40[1] + d40[2] + d40[3]) * scale;
      float s1 = (d41[0] + d41[1] + d41[2] + d41[3]) * scale;
      float mn = fmaxf(m, fmaxf(s0, s1));
      float p0 = __expf(s0 - mn);
      float p1 = __expf(s1 - mn);
      if (mn > m) {
        float al = __expf(m - mn);
        l *= al;
#pragma unroll
        for (int w = 0; w < 8; ++w) acc[w] *= al;
        m = mn;
      }
      l += p0 + p1;
      const f32x4* vr0 = &Vs[j * 8];
      const f32x4* vr1 = &Vs[(j + 1) * 8];
#pragma unroll
      for (int w = 0; w < 8; ++w) acc[w] += p0 * vr0[w] + p1 * vr1[w];
    }
  }
  float inv = 1.f / l;
  float* op = o + ((size_t)(b0 + bl) * 256 + tid) * DMODEL + hc;
#pragma unroll
  for (int w = 0; w < 8; ++w) *(f32x4*)(op + 4 * w) = acc[w] * inv;
}

// ---------------- query attention: block=batch, 256 thr=(head,row) ----------
__global__ __launch_bounds__(256) void k_attn_qry(const float* __restrict__ qkv,
    float* __restrict__ o) {
  __shared__ f32x4 Ks[32 * 64];
  __shared__ f32x4 Vs[32 * 64];
  int bl = blockIdx.x;
  int tid = threadIdx.x;
  const float* base = qkv + (size_t)bl * 32 * 768;
  for (int idx = tid; idx < 2048; idx += 256) {
    int s = idx >> 6, c = idx & 63;
    Ks[idx] = *(const f32x4*)(base + (size_t)s * 768 + 256 + c * 4);
    Vs[idx] = *(const f32x4*)(base + (size_t)s * 768 + 512 + c * 4);
  }
  __syncthreads();
  int h = tid >> 5, row = tid & 31;
  int hc = h * 32;
  f32x4 q[8], acc[8];
  const float* qp = base + (size_t)row * 768 + hc;
#pragma unroll
  for (int w = 0; w < 8; ++w) { q[w] = *(const f32x4*)(qp + 4 * w); acc[w] = 0.f; }
  float m = -1e30f, l = 0.f;
  const float scale = 0.17677669529663687f;
  for (int j = 0; j < 32; ++j) {
    const f32x4* kr = &Ks[j * 64 + h * 8];
    f32x4 da = q[0] * kr[0];
    f32x4 db = q[1] * kr[1];
#pragma unroll
    for (int w = 2; w < 8; w += 2) {
      da += q[w] * kr[w];
      db += q[w + 1] * kr[w + 1];
    }
    f32x4 d4 = da + db;
    float s_ = (d4[0] + d4[1] + d4[2] + d4[3]) * scale;
    float mn = fmaxf(m, s_);
    float p = __expf(s_ - mn);
    if (mn > m) {
      float al = __expf(m - mn);
      l *= al;
#pragma unroll
      for (int w = 0; w < 8; ++w) acc[w] *= al;
      m = mn;
    }
    l += p;
    const f32x4* vr = &Vs[j * 64 + h * 8];
#pragma unroll
    for (int w = 0; w < 8; ++w) acc[w] += p * vr[w];
  }
  float inv = 1.f / l;
  float* op = o + ((size_t)bl * 32 + row) * DMODEL + hc;
#pragma unroll
  for (int w = 0; w < 8; ++w) *(f32x4*)(op + 4 * w) = acc[w] * inv;
}

// ---------------- scoring stage 1: block=(batch, query-half) ----------------
__global__ __launch_bounds__(256) void k_score(
    const int* __restrict__ qids, const int* __restrict__ dids,
    const float* __restrict__ emb, const float* __restrict__ xq,
    const float* __restrict__ xd, const float* __restrict__ a_ptr,
    const float* __restrict__ mlp_w, float* __restrict__ part) {
  __shared__ float qmix[16 * 256];
  __shared__ float qks[4][16][11];
  __shared__ float qmask_s[16];
  __shared__ float mw_s[11];
  int blk = blockIdx.x;
  int b = blk >> 1, half = blk & 1;
  int tid = threadIdx.x;
  int wv = tid >> 6, lane = tid & 63;
  float av = a_ptr[0], aw = 1.f - av;
  for (int q = 0; q < 16; ++q) {
    int qg = half * 16 + q;
    int qid = qids[b * 32 + qg];
    float qm = qid > 0 ? 1.f : 0.f;
    float ev = emb[(size_t)qid * 256 + tid];
    float xv = xq[((size_t)b * 32 + qg) * 256 + tid];
    qmix[q * 256 + tid] = (av * ev + aw * xv) * qm;
    if (tid == 0) qmask_s[q] = qm;
  }
  if (tid < 11) mw_s[tid] = mlp_w[tid];
  __syncthreads();
  int j = tid;
  int did = dids[b * 256 + j];
  float dmask = did > 0 ? 1.f : 0.f;
  float sim[16];
#pragma unroll
  for (int q = 0; q < 16; ++q) sim[q] = 0.f;
  const float4* de = (const float4*)(emb + (size_t)did * 256);
  const float4* dxp = (const float4*)(xd + ((size_t)b * 256 + j) * 256);
  for (int c = 0; c < 4; ++c) {
    float4 dreg[16];
#pragma unroll
    for (int w = 0; w < 16; ++w) {
      float4 e = de[c * 16 + w], x = dxp[c * 16 + w];
      dreg[w].x = av * e.x + aw * x.x;
      dreg[w].y = av * e.y + aw * x.y;
      dreg[w].z = av * e.z + aw * x.z;
      dreg[w].w = av * e.w + aw * x.w;
    }
#pragma unroll
    for (int q = 0; q < 16; ++q) {
      const float4* qp = (const float4*)&qmix[q * 256 + c * 64];
      float d_ = 0.f;
#pragma unroll
      for (int w = 0; w < 16; ++w) {
        float4 t = qp[w];
        d_ += t.x * dreg[w].x + t.y * dreg[w].y + t.z * dreg[w].z + t.w * dreg[w].w;
      }
      sim[q] += d_;
    }
  }
  const float MU[11] = {1.f, 0.9f, 0.7f, 0.5f, 0.3f, 0.1f, -0.1f, -0.3f, -0.5f, -0.7f, -0.9f};
  const float IC[11] = {5e7f, 50.f, 50.f, 50.f, 50.f, 50.f, 50.f, 50.f, 50.f, 50.f, 50.f};
  for (int q = 0; q < 16; ++q) {
    float s = sim[q];
    float f = dmask * qmask_s[q];
#pragma unroll
    for (int k = 0; k < 11; ++k) {
      float d_ = s - MU[k];
      float v = expf(-d_ * d_ * IC[k]) * f;
#pragma unroll
      for (int o = 32; o > 0; o >>= 1) v += __shfl_xor(v, o);
      if (lane == 0) qks[wv][q][k] = v;
    }
  }
  __syncthreads();
  if (tid < 176) {
    int q = tid / 11, k = tid - q * 11;
    float kv = (qks[0][q][k] + qks[1][q][k]) + (qks[2][q][k] + qks[3][q][k]);
    qks[0][q][k] = mw_s[k] * (qmask_s[q] * logf(fmaxf(kv, 1e-10f))
                              + kv * (1.f / 256.f));
  }
  __syncthreads();
  if (tid < 16) {
    float p = 0.f;
#pragma unroll
    for (int k = 0; k < 11; ++k) p += qks[0][tid][k];
#pragma unroll
    for (int o = 8; o > 0; o >>= 1) p += __shfl_xor(p, o);
    if (tid == 0) part[blk] = p;
  }
}

// ---------------- scoring stage 2: combine half partials --------------------
__global__ __launch_bounds__(256) void k_score_fin(const float* __restrict__ part,
    float* __restrict__ out) {
  int b = threadIdx.x;
  out[b] = part[2 * b] + part[2 * b + 1];
}

extern "C" void kernel_launch(void* const* d_in, const int* in_sizes, int n_in,
                              void* d_out, int out_size, void* d_ws, size_t ws_size,
                              hipStream_t stream) {
  const int* qids = (const int*)d_in[0];
  const int* dids = (const int*)d_in[1];
  const float* emb = (const float*)d_in[2];
  const float* a = (const float*)d_in[3];
  const float* mlp_w = (const float*)d_in[4];
  const float* Wqkv = (const float*)d_in[5];
  const float* bqkv = (const float*)d_in[6];
  const float* Wo = (const float*)d_in[7];
  const float* bo = (const float*)d_in[8];
  const float* l1s = (const float*)d_in[9];
  const float* l1b = (const float*)d_in[10];
  const float* W1 = (const float*)d_in[11];
  const float* b1 = (const float*)d_in[12];
  const float* W2 = (const float*)d_in[13];
  const float* b2 = (const float*)d_in[14];
  const float* l2s = (const float*)d_in[15];
  const float* l2b = (const float*)d_in[16];
  float* out = (float*)d_out;
  float* ws = (float*)d_ws;

  const int TOK = 73728;                      // 65536 doc + 8192 query tokens
  size_t wsf = ws_size / 4;
  const size_t fixed = 2 * (size_t)TOK * 256 + 65536;  // x + t0 + pe

  int FW = 128, CB = 32;
  bool merged = false;
  if (fixed + (size_t)40960 * 768 <= wsf) {
    merged = true; FW = 256; CB = 128;                                     // 277MB
  } else if (fixed + (size_t)128 * 196608 <= wsf) {
    FW = 256; CB = 128;                                                    // 252MB
  } else if (fixed + (size_t)TOK * 256 <= wsf) {
    FW = 256; CB = 64;                                                     // 227MB
  } else {
    FW = 128; CB = 32;                                                     // 189MB
  }

  float* x       = ws;
  float* t0      = x + (size_t)TOK * 256;
  float* pe      = t0 + (size_t)TOK * 256;
  float* scratch = pe + 65536;   // qkv chunk | h_part | score partials

  k_pe<<<256, 256, 0, stream>>>(pe);
  k_embed<<<TOK / 4, 256, 0, stream>>>(dids, qids, emb, pe, x);

  for (int l = 0; l < 2; ++l) {
    const float* wq = Wqkv + (size_t)l * 768 * 256;
    const float* bq = bqkv + l * 768;
    const float* wo = Wo + (size_t)l * 256 * 256;
    const float* bo_ = bo + l * 256;
    const float* w1 = W1 + (size_t)l * 2048 * 256;
    const float* b1_ = b1 + l * 2048;
    const float* w2 = W2 + (size_t)l * 256 * 2048;
    const float* b2_ = b2 + l * 256;

    if (merged) {
      k_gemm<false, false><<<dim3(6, 256), 256, 0, stream>>>(
          x, wq, bq, scratch, 32768, 768, 256, 256);
      k_attn_doc<<<1024, 256, 0, stream>>>(scratch, t0, 0);
      k_gemm<false, false><<<dim3(6, 320), 256, 0, stream>>>(
          x + (size_t)32768 * 256, wq, bq, scratch, 40960, 768, 256, 256);
      k_attn_doc<<<1024, 256, 0, stream>>>(scratch, t0, 128);
      k_attn_qry<<<256, 256, 0, stream>>>(scratch + (size_t)32768 * 768,
                                          t0 + (size_t)65536 * 256);
    } else {
      for (int c = 0; c < 256; c += CB) {
        int Mc = CB * 256;
        k_gemm<false, false><<<dim3(6, Mc / 128), 256, 0, stream>>>(
            x + (size_t)c * 65536, wq, bq, scratch, Mc, 768, 256, 256);
        k_attn_doc<<<CB * 8, 256, 0, stream>>>(scratch, t0, c);
      }
      k_gemm<false, false><<<dim3(6, 64), 256, 0, stream>>>(
          x + (size_t)65536 * 256, wq, bq, scratch, 8192, 768, 256, 256);
      k_attn_qry<<<256, 256, 0, stream>>>(scratch, t0 + (size_t)65536 * 256);
    }
    // Wo + bias + residual + LN1, in-place into x
    k_gemm_ln<false><<<TOK / 64, 256, 0, stream>>>(t0, wo, bo_, x, t0,
        l1s + l * 256, l1b + l * 256, TOK, 256, 256);
    // FFN, ff-sliced (FW); last W2 slice fused with residual+LN2
    int nparts = 2048 / FW;
    for (int p = 0; p < nparts; ++p) {
      k_gemm<true, false><<<dim3(FW / 128, TOK / 128), 256, 0, stream>>>(
          x, w1 + (size_t)p * FW * 256, b1_ + p * FW, scratch, TOK, FW, 256, 256);
      if (p == 0)
        k_gemm<false, false><<<dim3(2, TOK / 128), 256, 0, stream>>>(
            scratch, w2, b2_, t0, TOK, 256, FW, 2048);
      else if (p < nparts - 1)
        k_gemm<false, true><<<dim3(2, TOK / 128), 256, 0, stream>>>(
            scratch, w2 + (size_t)p * FW, b2_, t0, TOK, 256, FW, 2048);
      else
        k_gemm_ln<true><<<TOK / 64, 256, 0, stream>>>(
            scratch, w2 + (size_t)p * FW, b2_, x, t0,
            l2s + l * 256, l2b + l * 256, TOK, FW, 2048);
    }
  }

  // scoring: 2 blocks per batch -> partials -> combine
  float* part = scratch;
  k_score<<<512, 256, 0, stream>>>(qids, dids, emb, x + (size_t)65536 * 256,
                                   x, a, mlp_w, part);
  k_score_fin<<<1, 256, 0, stream>>>(part, out);
}